// Round 1
// baseline (1088.991 us; speedup 1.0000x reference)
//
#include <hip/hip_runtime.h>
#include <math.h>

#define B_ 8
#define N_ 2048
#define C_ 512
#define K_ 8
#define EPS 1e-6f
#define GENO_RATIO 0.1f

// ---------------------------------------------------------------------------
// ws layout (float elements):
// [0,64)                geno logits [B,K]
// [64,128)              cnt (int)   [B,K]   -- list counters / usage counts
// [128,192)             mass        [B,K]
// [192,192+32768)       hsum        [B,K,C] -- weighted relu(h) sums
// [32960,32960+131072)  lw          [B,K,N] -- list weights
// [164032,+131072)      ln (int)    [B,K,N] -- list token indices
// total ~1.2 MB
// ---------------------------------------------------------------------------

// geno logits: one block per (b,k), 64 lanes reduce over C
__global__ __launch_bounds__(64) void k_geno(const float* __restrict__ geno_vec,
                                             const float* __restrict__ geno_w,
                                             const float* __restrict__ geno_b,
                                             float* __restrict__ geno_out) {
    int p = blockIdx.x; int b = p >> 3; int k = p & 7;
    int lane = threadIdx.x;
    float acc = 0.f;
    #pragma unroll
    for (int i = 0; i < C_ / 64; ++i) {
        int c = lane + 64 * i;
        acc += geno_vec[b * C_ + c] * geno_w[c * K_ + k];
    }
    #pragma unroll
    for (int off = 32; off > 0; off >>= 1) acc += __shfl_xor(acc, off, 64);
    if (lane == 0) geno_out[p] = acc + geno_b[k];
}

// gating: one wave per token. fp32 logits, top-2, softmax, build per-(b,k) lists.
__global__ __launch_bounds__(256) void k_gate(const float* __restrict__ tokens,
                                              const float* __restrict__ gate_w,
                                              const float* __restrict__ gate_b,
                                              const float* __restrict__ geno_out,
                                              int* __restrict__ cnt,
                                              float* __restrict__ mass,
                                              int* __restrict__ ln,
                                              float* __restrict__ lw) {
    int wave = threadIdx.x >> 6;
    int lane = threadIdx.x & 63;
    int t = blockIdx.x * 4 + wave;          // token id in [0, B*N)
    int b = t >> 11;                        // N = 2048
    int n = t & 2047;
    float acc[8] = {0.f,0.f,0.f,0.f,0.f,0.f,0.f,0.f};
    const float* trow = tokens + (size_t)t * C_;
    #pragma unroll
    for (int i = 0; i < C_ / 64; ++i) {
        int c = lane + 64 * i;
        float tv = trow[c];
        const float4* g4 = (const float4*)(gate_w + c * K_);
        float4 g0 = g4[0], g1 = g4[1];
        acc[0] = fmaf(tv, g0.x, acc[0]); acc[1] = fmaf(tv, g0.y, acc[1]);
        acc[2] = fmaf(tv, g0.z, acc[2]); acc[3] = fmaf(tv, g0.w, acc[3]);
        acc[4] = fmaf(tv, g1.x, acc[4]); acc[5] = fmaf(tv, g1.y, acc[5]);
        acc[6] = fmaf(tv, g1.z, acc[6]); acc[7] = fmaf(tv, g1.w, acc[7]);
    }
    #pragma unroll
    for (int off = 32; off > 0; off >>= 1) {
        #pragma unroll
        for (int j = 0; j < 8; ++j) acc[j] += __shfl_xor(acc[j], off, 64);
    }
    if (lane == 0) {
        float lg[8];
        #pragma unroll
        for (int j = 0; j < 8; ++j)
            lg[j] = acc[j] + gate_b[j] + GENO_RATIO * geno_out[b * K_ + j];
        // GATE_TEMP = 1.0 -> division is identity
        int i0 = 0; float v0 = lg[0];
        #pragma unroll
        for (int j = 1; j < 8; ++j) if (lg[j] > v0) { v0 = lg[j]; i0 = j; }
        int i1 = -1; float v1 = -1e30f;
        #pragma unroll
        for (int j = 0; j < 8; ++j) if (j != i0 && lg[j] > v1) { v1 = lg[j]; i1 = j; }
        // softmax over (v0 >= v1), clamp eps, renormalize
        float e = expf(v1 - v0);
        float w0 = 1.f / (1.f + e);
        float w1 = e / (1.f + e);
        w0 = fmaxf(w0, EPS); w1 = fmaxf(w1, EPS);
        float s = w0 + w1; w0 /= s; w1 /= s;
        int p0 = b * K_ + i0;
        int p1 = b * K_ + i1;
        int pos0 = atomicAdd(&cnt[p0], 1);
        ln[p0 * N_ + pos0] = n; lw[p0 * N_ + pos0] = w0;
        atomicAdd(&mass[p0], w0);
        int pos1 = atomicAdd(&cnt[p1], 1);
        ln[p1 * N_ + pos1] = n; lw[p1 * N_ + pos1] = w1;
        atomicAdd(&mass[p1], w1);
    }
}

// grouped GEMM1 + weighted relu accumulate:
// block tile: 64 tokens x 128 out-channels, K-chunks of 16, fp32.
// thread micro-tile 4x8 (channels split tx*4 and 64+tx*4 to avoid LDS conflicts)
__global__ __launch_bounds__(256) void k_ffn1(const float* __restrict__ tokens,
                                              const float* __restrict__ w1,
                                              const float* __restrict__ b1,
                                              const int* __restrict__ cnt,
                                              const int* __restrict__ ln,
                                              const float* __restrict__ lw,
                                              float* __restrict__ hsum) {
    int p = blockIdx.z; int b = p >> 3; int k = p & 7;
    int count = cnt[p];
    int m0 = blockIdx.x * 64;
    if (m0 >= count) return;

    __shared__ float As[16][64];
    __shared__ float Bs[16][128];
    __shared__ int   ns[64];
    __shared__ float wls[64];
    __shared__ float hsum_s[128];

    int tid = threadIdx.x;
    if (tid < 64) {
        int mi = m0 + tid;
        if (mi < count) { ns[tid] = ln[p * N_ + mi]; wls[tid] = lw[p * N_ + mi]; }
        else            { ns[tid] = 0;               wls[tid] = 0.f; }
    } else if (tid < 192) {
        hsum_s[tid - 64] = 0.f;
    }
    __syncthreads();

    int ty = tid >> 4, tx = tid & 15;
    int n0 = blockIdx.y * 128;
    float acc[4][8];
    #pragma unroll
    for (int i = 0; i < 4; ++i)
        #pragma unroll
        for (int j = 0; j < 8; ++j) acc[i][j] = 0.f;

    const float* w1k = w1 + (size_t)k * C_ * C_ + n0;

    for (int c0 = 0; c0 < C_; c0 += 16) {
        // stage A: gathered token rows, transposed to As[kc][m]
        {
            int m = tid >> 2; int cc = (tid & 3) * 4;
            float4 av = *(const float4*)(tokens + ((size_t)(b * N_ + ns[m])) * C_ + c0 + cc);
            As[cc + 0][m] = av.x; As[cc + 1][m] = av.y;
            As[cc + 2][m] = av.z; As[cc + 3][m] = av.w;
        }
        // stage B: w1[k][c0+kc][n0 .. n0+127], fully coalesced
        {
            int f = tid; int kc = f >> 5; int nn = (f & 31) * 4;
            *(float4*)&Bs[kc][nn] = *(const float4*)(w1k + (size_t)(c0 + kc) * C_ + nn);
            f = tid + 256; kc = f >> 5; nn = (f & 31) * 4;
            *(float4*)&Bs[kc][nn] = *(const float4*)(w1k + (size_t)(c0 + kc) * C_ + nn);
        }
        __syncthreads();
        #pragma unroll
        for (int kk = 0; kk < 16; ++kk) {
            float4 af  = *(const float4*)&As[kk][ty * 4];
            float4 bf0 = *(const float4*)&Bs[kk][tx * 4];
            float4 bf1 = *(const float4*)&Bs[kk][64 + tx * 4];
            float a[4]  = {af.x, af.y, af.z, af.w};
            float bv[8] = {bf0.x, bf0.y, bf0.z, bf0.w, bf1.x, bf1.y, bf1.z, bf1.w};
            #pragma unroll
            for (int i = 0; i < 4; ++i)
                #pragma unroll
                for (int j = 0; j < 8; ++j)
                    acc[i][j] = fmaf(a[i], bv[j], acc[i][j]);
        }
        __syncthreads();
    }

    // epilogue: +b1, relu, gate-weighted sum over the 4 tokens of this thread
    float part[8] = {0.f,0.f,0.f,0.f,0.f,0.f,0.f,0.f};
    #pragma unroll
    for (int i = 0; i < 4; ++i) {
        float w = wls[ty * 4 + i];
        #pragma unroll
        for (int j = 0; j < 8; ++j) {
            int ch = (j < 4) ? (tx * 4 + j) : (64 + tx * 4 + (j - 4));
            float h = acc[i][j] + b1[k * C_ + n0 + ch];
            part[j] += w * fmaxf(h, 0.f);
        }
    }
    #pragma unroll
    for (int j = 0; j < 8; ++j) {
        int ch = (j < 4) ? (tx * 4 + j) : (64 + tx * 4 + (j - 4));
        atomicAdd(&hsum_s[ch], part[j]);
    }
    __syncthreads();
    if (tid < 128) atomicAdd(&hsum[(size_t)p * C_ + n0 + tid], hsum_s[tid]);
}

// combine: centers[b,k,e] = (hsum[b,k,:]@w2[k] + b2[k,e]*mass) / max(mass,eps)
__global__ __launch_bounds__(64) void k_combine(const float* __restrict__ hsum,
                                                const float* __restrict__ w2,
                                                const float* __restrict__ b2,
                                                const float* __restrict__ mass,
                                                float* __restrict__ out) {
    int k = blockIdx.y;
    int e = blockIdx.x * 64 + threadIdx.x;
    __shared__ float hs[8][C_];
    for (int i = threadIdx.x; i < 8 * C_; i += 64) {
        int b = i >> 9, c = i & (C_ - 1);
        hs[b][c] = hsum[((size_t)(b * K_ + k)) * C_ + c];
    }
    __syncthreads();
    float acc[8] = {0.f,0.f,0.f,0.f,0.f,0.f,0.f,0.f};
    const float* w2k = w2 + (size_t)k * C_ * C_;
    for (int c = 0; c < C_; ++c) {
        float wv = w2k[(size_t)c * C_ + e];
        #pragma unroll
        for (int b = 0; b < 8; ++b) acc[b] = fmaf(hs[b][c], wv, acc[b]);
    }
    float bias = b2[k * C_ + e];
    #pragma unroll
    for (int b = 0; b < 8; ++b) {
        float m = mass[b * K_ + k];
        float cs = acc[b] + bias * m;
        out[((size_t)(b * K_ + k)) * C_ + e] = cs / fmaxf(m, EPS);
    }
}

// lb_loss from integer hit counts (exact)
__global__ void k_loss(const int* __restrict__ cnt, float* __restrict__ out) {
    if (threadIdx.x == 0 && blockIdx.x == 0) {
        float u[8]; float s = 0.f;
        for (int k = 0; k < 8; ++k) {
            int ck = 0;
            for (int b = 0; b < 8; ++b) ck += cnt[b * K_ + k];
            u[k] = (float)ck / (float)(B_ * N_);
            s += u[k];
        }
        float mean = s / 8.f;
        float var = 0.f;
        for (int k = 0; k < 8; ++k) { float d = u[k] - mean; var += d * d; }
        var /= 8.f;
        float denom = mean + EPS;
        out[B_ * K_ * C_] = var / (denom * denom);
    }
}

extern "C" void kernel_launch(void* const* d_in, const int* in_sizes, int n_in,
                              void* d_out, int out_size, void* d_ws, size_t ws_size,
                              hipStream_t stream) {
    (void)in_sizes; (void)n_in; (void)out_size; (void)ws_size;
    const float* tokens   = (const float*)d_in[0];
    const float* geno_vec = (const float*)d_in[1];
    const float* gate_w   = (const float*)d_in[2];
    const float* gate_b   = (const float*)d_in[3];
    const float* geno_w   = (const float*)d_in[4];
    const float* geno_b   = (const float*)d_in[5];
    const float* w1       = (const float*)d_in[6];
    const float* b1       = (const float*)d_in[7];
    const float* w2       = (const float*)d_in[8];
    const float* b2       = (const float*)d_in[9];
    float* out = (float*)d_out;
    float* ws  = (float*)d_ws;

    float* geno_out = ws;                               // 64
    int*   cnt      = (int*)(ws + 64);                  // 64
    float* mass     = ws + 128;                         // 64
    float* hsum     = ws + 192;                         // 32768
    float* lw       = ws + 192 + B_ * K_ * C_;          // 131072
    int*   ln       = (int*)(ws + 192 + B_ * K_ * C_ + B_ * K_ * N_);

    // zero cnt, mass, hsum (contiguous region)
    hipMemsetAsync(ws + 64, 0, (size_t)(64 + 64 + B_ * K_ * C_) * sizeof(float), stream);

    k_geno<<<dim3(B_ * K_), dim3(64), 0, stream>>>(geno_vec, geno_w, geno_b, geno_out);
    k_gate<<<dim3(B_ * N_ / 4), dim3(256), 0, stream>>>(tokens, gate_w, gate_b, geno_out,
                                                        cnt, mass, ln, lw);
    k_ffn1<<<dim3(N_ / 64, C_ / 128, B_ * K_), dim3(256), 0, stream>>>(tokens, w1, b1,
                                                                       cnt, ln, lw, hsum);
    k_combine<<<dim3(C_ / 64, K_), dim3(64), 0, stream>>>(hsum, w2, b2, mass, out);
    k_loss<<<1, 64, 0, stream>>>(cnt, out);
}

// Round 2
// 660.441 us; speedup vs baseline: 1.6489x; 1.6489x over previous
//
#include <hip/hip_runtime.h>
#include <math.h>

#define B_ 8
#define N_ 2048
#define C_ 512
#define K_ 8
#define EPS 1e-6f
#define GENO_RATIO 0.1f

typedef __bf16 bf16x8 __attribute__((ext_vector_type(8)));
typedef float f32x4 __attribute__((ext_vector_type(4)));

__device__ __forceinline__ ushort f2bf(float x) {
    unsigned int u = __float_as_uint(x);
    u += 0x7fffu + ((u >> 16) & 1u);   // RNE (inputs are finite)
    return (ushort)(u >> 16);
}

// ---------------------------------------------------------------------------
// ws layout (float element offsets):
// [0,64)            geno logits [B,K]
// [64,128)          cnt (int)   [B,K]
// [128,192)         mass        [B,K]
// [192,32960)       hsum        [B,K,C]
// [32960,65728)     ctmp        [B,K,C]   (combine partials)
// [65728,196800)    lw          [B,K,N]
// [196800,327872)   ln (int)    [B,K,N]
// [327872,...)      w1t (bf16)  [K,C,C]   4 MB
// ---------------------------------------------------------------------------

__global__ __launch_bounds__(64) void k_geno(const float* __restrict__ geno_vec,
                                             const float* __restrict__ geno_w,
                                             const float* __restrict__ geno_b,
                                             float* __restrict__ geno_out) {
    int p = blockIdx.x; int b = p >> 3; int k = p & 7;
    int lane = threadIdx.x;
    float acc = 0.f;
    #pragma unroll
    for (int i = 0; i < C_ / 64; ++i) {
        int c = lane + 64 * i;
        acc += geno_vec[b * C_ + c] * geno_w[c * K_ + k];
    }
    #pragma unroll
    for (int off = 32; off > 0; off >>= 1) acc += __shfl_xor(acc, off, 64);
    if (lane == 0) geno_out[p] = acc + geno_b[k];
}

// gating: one wave per token. fp32 logits, top-2, softmax, per-(b,k) lists.
__global__ __launch_bounds__(256) void k_gate(const float* __restrict__ tokens,
                                              const float* __restrict__ gate_w,
                                              const float* __restrict__ gate_b,
                                              const float* __restrict__ geno_out,
                                              int* __restrict__ cnt,
                                              float* __restrict__ mass,
                                              int* __restrict__ ln,
                                              float* __restrict__ lw) {
    int wave = threadIdx.x >> 6;
    int lane = threadIdx.x & 63;
    int t = blockIdx.x * 4 + wave;
    int b = t >> 11;
    int n = t & 2047;
    float acc[8] = {0.f,0.f,0.f,0.f,0.f,0.f,0.f,0.f};
    const float* trow = tokens + (size_t)t * C_;
    #pragma unroll
    for (int i = 0; i < C_ / 64; ++i) {
        int c = lane + 64 * i;
        float tv = trow[c];
        const float4* g4 = (const float4*)(gate_w + c * K_);
        float4 g0 = g4[0], g1 = g4[1];
        acc[0] = fmaf(tv, g0.x, acc[0]); acc[1] = fmaf(tv, g0.y, acc[1]);
        acc[2] = fmaf(tv, g0.z, acc[2]); acc[3] = fmaf(tv, g0.w, acc[3]);
        acc[4] = fmaf(tv, g1.x, acc[4]); acc[5] = fmaf(tv, g1.y, acc[5]);
        acc[6] = fmaf(tv, g1.z, acc[6]); acc[7] = fmaf(tv, g1.w, acc[7]);
    }
    #pragma unroll
    for (int off = 32; off > 0; off >>= 1) {
        #pragma unroll
        for (int j = 0; j < 8; ++j) acc[j] += __shfl_xor(acc[j], off, 64);
    }
    if (lane == 0) {
        float lg[8];
        #pragma unroll
        for (int j = 0; j < 8; ++j)
            lg[j] = acc[j] + gate_b[j] + GENO_RATIO * geno_out[b * K_ + j];
        int i0 = 0; float v0 = lg[0];
        #pragma unroll
        for (int j = 1; j < 8; ++j) if (lg[j] > v0) { v0 = lg[j]; i0 = j; }
        int i1 = -1; float v1 = -1e30f;
        #pragma unroll
        for (int j = 0; j < 8; ++j) if (j != i0 && lg[j] > v1) { v1 = lg[j]; i1 = j; }
        float e = expf(v1 - v0);
        float w0 = 1.f / (1.f + e);
        float w1 = e / (1.f + e);
        w0 = fmaxf(w0, EPS); w1 = fmaxf(w1, EPS);
        float s = w0 + w1; w0 /= s; w1 /= s;
        int p0 = b * K_ + i0;
        int p1 = b * K_ + i1;
        int pos0 = atomicAdd(&cnt[p0], 1);
        ln[p0 * N_ + pos0] = n; lw[p0 * N_ + pos0] = w0;
        atomicAdd(&mass[p0], w0);
        int pos1 = atomicAdd(&cnt[p1], 1);
        ln[p1 * N_ + pos1] = n; lw[p1 * N_ + pos1] = w1;
        atomicAdd(&mass[p1], w1);
    }
}

// transpose + convert: w1t[k][n][c] (bf16) = w1[k][c][n]
__global__ __launch_bounds__(256) void k_w1t(const float* __restrict__ w1,
                                             ushort* __restrict__ w1t) {
    int k = blockIdx.z; int c0 = blockIdx.x * 64; int n0 = blockIdx.y * 64;
    __shared__ float tile[64][65];
    int t = threadIdx.x;
    int tr = t >> 4;          // 0..15
    int tc4 = (t & 15) * 4;   // 0..60
    const float* src = w1 + (size_t)k * C_ * C_;
    #pragma unroll
    for (int i = 0; i < 4; ++i) {
        int c = c0 + tr + i * 16;
        float4 v = *(const float4*)(src + (size_t)c * C_ + n0 + tc4);
        tile[tr + i * 16][tc4 + 0] = v.x; tile[tr + i * 16][tc4 + 1] = v.y;
        tile[tr + i * 16][tc4 + 2] = v.z; tile[tr + i * 16][tc4 + 3] = v.w;
    }
    __syncthreads();
    ushort* dst = w1t + (size_t)k * C_ * C_;
    #pragma unroll
    for (int i = 0; i < 4; ++i) {
        int rr = tr + i * 16;
        int n = n0 + rr;
        uint2 o;
        o.x = (unsigned)f2bf(tile[tc4 + 0][rr]) | ((unsigned)f2bf(tile[tc4 + 1][rr]) << 16);
        o.y = (unsigned)f2bf(tile[tc4 + 2][rr]) | ((unsigned)f2bf(tile[tc4 + 3][rr]) << 16);
        *(uint2*)(dst + (size_t)n * C_ + c0 + tc4) = o;
    }
}

// grouped GEMM1 (MFMA bf16) + bias + relu + gate-weighted accumulate into hsum
// block: 4 waves; tile 64 tokens x 128 channels; BK=32 staged in padded LDS.
__global__ __launch_bounds__(256) void k_ffn1(const float* __restrict__ tokens,
                                              const ushort* __restrict__ w1t,
                                              const float* __restrict__ b1,
                                              const int* __restrict__ cnt,
                                              const int* __restrict__ ln,
                                              const float* __restrict__ lw,
                                              float* __restrict__ hsum) {
    int p = blockIdx.z; int b = p >> 3; int k = p & 7;
    int count = cnt[p];
    int m0 = blockIdx.x * 64;
    if (m0 >= count) return;
    int n0 = blockIdx.y * 128;

    __shared__ unsigned int Bs[128 * 20];  // 128 rows x 32 bf16, row stride 20 dwords (80B)
    __shared__ int   ns_s[64];
    __shared__ float wls_s[64];
    __shared__ float hsum_s[128];

    int tid = threadIdx.x;
    if (tid < 64) {
        int mi = m0 + tid;
        bool v = mi < count;
        ns_s[tid]  = v ? ln[p * N_ + mi] : 0;
        wls_s[tid] = v ? lw[p * N_ + mi] : 0.f;
    } else if (tid < 192) {
        hsum_s[tid - 64] = 0.f;
    }
    __syncthreads();

    int wv = tid >> 6, lane = tid & 63;
    int ln15 = lane & 15, q = lane >> 4;
    int mrow = (wv << 4) + ln15;
    const float* arow = tokens + ((size_t)(b * N_ + ns_s[mrow])) * C_ + q * 8;

    // B staging addresses: thread loads 2x16B chunks of w1t[k][n0..n0+128][c0..c0+32]
    const ushort* w1k = w1t + (size_t)k * C_ * C_;
    int sn0 = tid >> 2,          sc0 = (tid & 3);         // chunk 0: row sn0
    int sn1 = (tid + 256) >> 2,  sc1 = ((tid + 256) & 3); // chunk 1

    f32x4 acc[8];
    #pragma unroll
    for (int i = 0; i < 8; ++i) acc[i] = (f32x4){0.f, 0.f, 0.f, 0.f};

    for (int c0 = 0; c0 < C_; c0 += 32) {
        __syncthreads();  // previous iteration's LDS reads done
        {
            uint4 v0 = *(const uint4*)(w1k + (size_t)(n0 + sn0) * C_ + c0 + sc0 * 8);
            uint4 v1 = *(const uint4*)(w1k + (size_t)(n0 + sn1) * C_ + c0 + sc1 * 8);
            *(uint4*)&Bs[sn0 * 20 + sc0 * 4] = v0;
            *(uint4*)&Bs[sn1 * 20 + sc1 * 4] = v1;
        }
        // A fragment: gathered global load + RNE convert (m=lane&15, k=q*8+j)
        float4 av0 = *(const float4*)(arow + c0);
        float4 av1 = *(const float4*)(arow + c0 + 4);
        union { bf16x8 v; ushort s[8]; } au;
        au.s[0] = f2bf(av0.x); au.s[1] = f2bf(av0.y);
        au.s[2] = f2bf(av0.z); au.s[3] = f2bf(av0.w);
        au.s[4] = f2bf(av1.x); au.s[5] = f2bf(av1.y);
        au.s[6] = f2bf(av1.z); au.s[7] = f2bf(av1.w);
        __syncthreads();  // staging visible
        #pragma unroll
        for (int nt = 0; nt < 8; ++nt) {
            bf16x8 bfrag = *(const bf16x8*)&Bs[(nt * 16 + ln15) * 20 + q * 4];
            acc[nt] = __builtin_amdgcn_mfma_f32_16x16x32_bf16(au.v, bfrag, acc[nt], 0, 0, 0);
        }
    }

    // epilogue: D rows m = q*4+reg (within wave tile), col n = nt*16 + ln15
    float wr[4];
    #pragma unroll
    for (int r = 0; r < 4; ++r) wr[r] = wls_s[(wv << 4) + q * 4 + r];
    const float* b1p = b1 + k * C_ + n0 + ln15;
    #pragma unroll
    for (int nt = 0; nt < 8; ++nt) {
        float bias = b1p[nt * 16];
        float partv = 0.f;
        #pragma unroll
        for (int r = 0; r < 4; ++r)
            partv += wr[r] * fmaxf(acc[nt][r] + bias, 0.f);
        atomicAdd(&hsum_s[nt * 16 + ln15], partv);
    }
    __syncthreads();
    if (tid < 128) atomicAdd(&hsum[(size_t)p * C_ + n0 + tid], hsum_s[tid]);
}

// combine partials: ctmp[b,k,e] += sum_{c in chunk} hsum[b,k,c] * w2[k,c,e]
__global__ __launch_bounds__(256) void k_comb(const float* __restrict__ hsum,
                                              const float* __restrict__ w2,
                                              float* __restrict__ ctmp) {
    int et = blockIdx.x, k = blockIdx.y, cc = blockIdx.z;
    int e0 = et * 64, c0 = cc * 128;
    __shared__ float hs[8][128];
    int t = threadIdx.x;
    for (int i = t; i < 1024; i += 256) {
        int b = i >> 7, c = i & 127;
        hs[b][c] = hsum[(size_t)((b * 8 + k) << 9) + c0 + c];
    }
    __syncthreads();
    int e = e0 + (t & 63); int g = t >> 6;
    float a0 = 0.f, a1 = 0.f;
    const float* w2p = w2 + (size_t)k * C_ * C_ + e;
    #pragma unroll 4
    for (int c = 0; c < 128; ++c) {
        float wv = w2p[(size_t)(c0 + c) * C_];
        a0 = fmaf(hs[g][c], wv, a0);
        a1 = fmaf(hs[g + 4][c], wv, a1);
    }
    atomicAdd(&ctmp[((g * 8 + k) << 9) + e], a0);
    atomicAdd(&ctmp[(((g + 4) * 8 + k) << 9) + e], a1);
}

// finalize: centers = (ctmp + b2*mass)/max(mass,eps); block0/thread0 writes lb_loss
__global__ __launch_bounds__(256) void k_fin(const float* __restrict__ ctmp,
                                             const float* __restrict__ b2,
                                             const float* __restrict__ mass,
                                             const int* __restrict__ cnt,
                                             float* __restrict__ out) {
    int i = blockIdx.x * 256 + threadIdx.x;  // 0..32767
    int b = i >> 12; int ke = i & 4095; int k = ke >> 9;
    float m = mass[b * 8 + k];
    out[i] = (ctmp[i] + b2[ke] * m) / fmaxf(m, EPS);
    if (i == 0) {
        float u[8]; float s = 0.f;
        for (int kk = 0; kk < 8; ++kk) {
            int ck = 0;
            for (int bb = 0; bb < 8; ++bb) ck += cnt[bb * K_ + kk];
            u[kk] = (float)ck / (float)(B_ * N_);
            s += u[kk];
        }
        float mean = s / 8.f;
        float var = 0.f;
        for (int kk = 0; kk < 8; ++kk) { float d = u[kk] - mean; var += d * d; }
        var /= 8.f;
        float denom = mean + EPS;
        out[B_ * K_ * C_] = var / (denom * denom);
    }
}

extern "C" void kernel_launch(void* const* d_in, const int* in_sizes, int n_in,
                              void* d_out, int out_size, void* d_ws, size_t ws_size,
                              hipStream_t stream) {
    (void)in_sizes; (void)n_in; (void)out_size; (void)ws_size;
    const float* tokens   = (const float*)d_in[0];
    const float* geno_vec = (const float*)d_in[1];
    const float* gate_w   = (const float*)d_in[2];
    const float* gate_b   = (const float*)d_in[3];
    const float* geno_w   = (const float*)d_in[4];
    const float* geno_b   = (const float*)d_in[5];
    const float* w1       = (const float*)d_in[6];
    const float* b1       = (const float*)d_in[7];
    const float* w2       = (const float*)d_in[8];
    const float* b2       = (const float*)d_in[9];
    float* out = (float*)d_out;
    float* ws  = (float*)d_ws;

    float*  geno_out = ws;                       // 64
    int*    cnt      = (int*)(ws + 64);          // 64
    float*  mass     = ws + 128;                 // 64
    float*  hsum     = ws + 192;                 // 32768
    float*  ctmp     = ws + 32960;               // 32768
    float*  lw       = ws + 65728;               // 131072
    int*    ln       = (int*)(ws + 196800);      // 131072
    ushort* w1t      = (ushort*)(ws + 327872);   // 2097152 bf16 (4 MB)

    // zero cnt, mass, hsum, ctmp (contiguous)
    hipMemsetAsync(ws + 64, 0, (size_t)(64 + 64 + 2 * B_ * K_ * C_) * sizeof(float), stream);

    k_geno<<<dim3(B_ * K_), dim3(64), 0, stream>>>(geno_vec, geno_w, geno_b, geno_out);
    k_w1t<<<dim3(8, 8, K_), dim3(256), 0, stream>>>(w1, w1t);
    k_gate<<<dim3(B_ * N_ / 4), dim3(256), 0, stream>>>(tokens, gate_w, gate_b, geno_out,
                                                        cnt, mass, ln, lw);
    k_ffn1<<<dim3(N_ / 64, C_ / 128, B_ * K_), dim3(256), 0, stream>>>(tokens, w1t, b1,
                                                                       cnt, ln, lw, hsum);
    k_comb<<<dim3(8, K_, 4), dim3(256), 0, stream>>>(hsum, w2, ctmp);
    k_fin<<<dim3(128), dim3(256), 0, stream>>>(ctmp, b2, mass, cnt, out);
}

// Round 3
// 357.373 us; speedup vs baseline: 3.0472x; 1.8480x over previous
//
#include <hip/hip_runtime.h>
#include <math.h>

#define B_ 8
#define N_ 2048
#define C_ 512
#define K_ 8
#define EPS 1e-6f
#define GENO_RATIO 0.1f

typedef __bf16 bf16x8 __attribute__((ext_vector_type(8)));
typedef float f32x4 __attribute__((ext_vector_type(4)));

__device__ __forceinline__ ushort f2bf(float x) {
    unsigned int u = __float_as_uint(x);
    u += 0x7fffu + ((u >> 16) & 1u);   // RNE (inputs are finite)
    return (ushort)(u >> 16);
}

// ---------------------------------------------------------------------------
// ws layout (float element offsets):
// [0,64)            geno logits [B,K]
// [64,128)          cnt (int)   [B,K]
// [128,192)         mass        [B,K]
// [192,32960)       hsum        [B,K,C]     (also overlaid: tpi[16384] int +
// [32960,65728)     ctmp        [B,K,C]      tpw[16384] float2 before memset)
// [65728,196800)    lw          [B,K,N]
// [196800,327872)   ln (int)    [B,K,N]
// [327872,...)      w1t (bf16)  [K,C,C]   4 MB
// ---------------------------------------------------------------------------

__global__ __launch_bounds__(64) void k_geno(const float* __restrict__ geno_vec,
                                             const float* __restrict__ geno_w,
                                             const float* __restrict__ geno_b,
                                             float* __restrict__ geno_out) {
    int p = blockIdx.x; int b = p >> 3; int k = p & 7;
    int lane = threadIdx.x;
    float acc = 0.f;
    #pragma unroll
    for (int i = 0; i < C_ / 64; ++i) {
        int c = lane + 64 * i;
        acc += geno_vec[b * C_ + c] * geno_w[c * K_ + k];
    }
    #pragma unroll
    for (int off = 32; off > 0; off >>= 1) acc += __shfl_xor(acc, off, 64);
    if (lane == 0) geno_out[p] = acc + geno_b[k];
}

// gating: one wave per token. fp32 GEMV + top-2 + softmax. NO atomics —
// writes per-token picks to tpi/tpw.
__global__ __launch_bounds__(256) void k_gate(const float* __restrict__ tokens,
                                              const float* __restrict__ gate_w,
                                              const float* __restrict__ gate_b,
                                              const float* __restrict__ geno_out,
                                              int* __restrict__ tpi,
                                              float2* __restrict__ tpw) {
    int wave = threadIdx.x >> 6;
    int lane = threadIdx.x & 63;
    int t = blockIdx.x * 4 + wave;
    int b = t >> 11;
    float acc[8] = {0.f,0.f,0.f,0.f,0.f,0.f,0.f,0.f};
    const float* trow = tokens + (size_t)t * C_;
    #pragma unroll
    for (int i = 0; i < C_ / 64; ++i) {
        int c = lane + 64 * i;
        float tv = trow[c];
        const float4* g4 = (const float4*)(gate_w + c * K_);
        float4 g0 = g4[0], g1 = g4[1];
        acc[0] = fmaf(tv, g0.x, acc[0]); acc[1] = fmaf(tv, g0.y, acc[1]);
        acc[2] = fmaf(tv, g0.z, acc[2]); acc[3] = fmaf(tv, g0.w, acc[3]);
        acc[4] = fmaf(tv, g1.x, acc[4]); acc[5] = fmaf(tv, g1.y, acc[5]);
        acc[6] = fmaf(tv, g1.z, acc[6]); acc[7] = fmaf(tv, g1.w, acc[7]);
    }
    #pragma unroll
    for (int off = 32; off > 0; off >>= 1) {
        #pragma unroll
        for (int j = 0; j < 8; ++j) acc[j] += __shfl_xor(acc[j], off, 64);
    }
    if (lane == 0) {
        float lg[8];
        #pragma unroll
        for (int j = 0; j < 8; ++j)
            lg[j] = acc[j] + gate_b[j] + GENO_RATIO * geno_out[b * K_ + j];
        int i0 = 0; float v0 = lg[0];
        #pragma unroll
        for (int j = 1; j < 8; ++j) if (lg[j] > v0) { v0 = lg[j]; i0 = j; }
        int i1 = -1; float v1 = -1e30f;
        #pragma unroll
        for (int j = 0; j < 8; ++j) if (j != i0 && lg[j] > v1) { v1 = lg[j]; i1 = j; }
        float e = expf(v1 - v0);
        float w0 = 1.f / (1.f + e);
        float w1 = e / (1.f + e);
        w0 = fmaxf(w0, EPS); w1 = fmaxf(w1, EPS);
        float s = w0 + w1; w0 /= s; w1 /= s;
        tpi[t] = i0 | (i1 << 4);
        tpw[t] = make_float2(w0, w1);
    }
}

// list build: one block per batch b; LDS counters only, zero global atomics.
__global__ __launch_bounds__(1024) void k_build(const int* __restrict__ tpi,
                                                const float2* __restrict__ tpw,
                                                int* __restrict__ cnt,
                                                float* __restrict__ mass,
                                                int* __restrict__ ln,
                                                float* __restrict__ lw) {
    int b = blockIdx.x;
    __shared__ int   lcnt[8];
    __shared__ float lmass[8];
    int tid = threadIdx.x;
    if (tid < 8) { lcnt[tid] = 0; lmass[tid] = 0.f; }
    __syncthreads();
    for (int n = tid; n < N_; n += 1024) {
        int pk = tpi[b * N_ + n];
        float2 w = tpw[b * N_ + n];
        int i0 = pk & 15, i1 = pk >> 4;
        int pos0 = atomicAdd(&lcnt[i0], 1);
        ln[(b * 8 + i0) * N_ + pos0] = n;
        lw[(b * 8 + i0) * N_ + pos0] = w.x;
        atomicAdd(&lmass[i0], w.x);
        int pos1 = atomicAdd(&lcnt[i1], 1);
        ln[(b * 8 + i1) * N_ + pos1] = n;
        lw[(b * 8 + i1) * N_ + pos1] = w.y;
        atomicAdd(&lmass[i1], w.y);
    }
    __syncthreads();
    if (tid < 8) {
        cnt[b * 8 + tid]  = lcnt[tid];
        mass[b * 8 + tid] = lmass[tid];
    }
}

// transpose + convert: w1t[k][n][c] (bf16) = w1[k][c][n]
__global__ __launch_bounds__(256) void k_w1t(const float* __restrict__ w1,
                                             ushort* __restrict__ w1t) {
    int k = blockIdx.z; int c0 = blockIdx.x * 64; int n0 = blockIdx.y * 64;
    __shared__ float tile[64][65];
    int t = threadIdx.x;
    int tr = t >> 4;          // 0..15
    int tc4 = (t & 15) * 4;   // 0..60
    const float* src = w1 + (size_t)k * C_ * C_;
    #pragma unroll
    for (int i = 0; i < 4; ++i) {
        int c = c0 + tr + i * 16;
        float4 v = *(const float4*)(src + (size_t)c * C_ + n0 + tc4);
        tile[tr + i * 16][tc4 + 0] = v.x; tile[tr + i * 16][tc4 + 1] = v.y;
        tile[tr + i * 16][tc4 + 2] = v.z; tile[tr + i * 16][tc4 + 3] = v.w;
    }
    __syncthreads();
    ushort* dst = w1t + (size_t)k * C_ * C_;
    #pragma unroll
    for (int i = 0; i < 4; ++i) {
        int rr = tr + i * 16;
        int n = n0 + rr;
        uint2 o;
        o.x = (unsigned)f2bf(tile[tc4 + 0][rr]) | ((unsigned)f2bf(tile[tc4 + 1][rr]) << 16);
        o.y = (unsigned)f2bf(tile[tc4 + 2][rr]) | ((unsigned)f2bf(tile[tc4 + 3][rr]) << 16);
        *(uint2*)(dst + (size_t)n * C_ + c0 + tc4) = o;
    }
}

// grouped GEMM1 (MFMA bf16) + bias + relu + gate-weighted accumulate into hsum
__global__ __launch_bounds__(256) void k_ffn1(const float* __restrict__ tokens,
                                              const ushort* __restrict__ w1t,
                                              const float* __restrict__ b1,
                                              const int* __restrict__ cnt,
                                              const int* __restrict__ ln,
                                              const float* __restrict__ lw,
                                              float* __restrict__ hsum) {
    int p = blockIdx.z; int b = p >> 3; int k = p & 7;
    int count = cnt[p];
    int m0 = blockIdx.x * 64;
    if (m0 >= count) return;
    int n0 = blockIdx.y * 128;

    __shared__ unsigned int Bs[128 * 20];  // 128 rows x 32 bf16, stride 20 dwords
    __shared__ int   ns_s[64];
    __shared__ float wls_s[64];
    __shared__ float hsum_s[128];

    int tid = threadIdx.x;
    if (tid < 64) {
        int mi = m0 + tid;
        bool v = mi < count;
        ns_s[tid]  = v ? ln[p * N_ + mi] : 0;
        wls_s[tid] = v ? lw[p * N_ + mi] : 0.f;
    } else if (tid < 192) {
        hsum_s[tid - 64] = 0.f;
    }
    __syncthreads();

    int wv = tid >> 6, lane = tid & 63;
    int ln15 = lane & 15, q = lane >> 4;
    int mrow = (wv << 4) + ln15;
    const float* arow = tokens + ((size_t)(b * N_ + ns_s[mrow])) * C_ + q * 8;

    const ushort* w1k = w1t + (size_t)k * C_ * C_;
    int sn0 = tid >> 2,          sc0 = (tid & 3);
    int sn1 = (tid + 256) >> 2,  sc1 = ((tid + 256) & 3);

    f32x4 acc[8];
    #pragma unroll
    for (int i = 0; i < 8; ++i) acc[i] = (f32x4){0.f, 0.f, 0.f, 0.f};

    for (int c0 = 0; c0 < C_; c0 += 32) {
        __syncthreads();
        {
            uint4 v0 = *(const uint4*)(w1k + (size_t)(n0 + sn0) * C_ + c0 + sc0 * 8);
            uint4 v1 = *(const uint4*)(w1k + (size_t)(n0 + sn1) * C_ + c0 + sc1 * 8);
            *(uint4*)&Bs[sn0 * 20 + sc0 * 4] = v0;
            *(uint4*)&Bs[sn1 * 20 + sc1 * 4] = v1;
        }
        float4 av0 = *(const float4*)(arow + c0);
        float4 av1 = *(const float4*)(arow + c0 + 4);
        union { bf16x8 v; ushort s[8]; } au;
        au.s[0] = f2bf(av0.x); au.s[1] = f2bf(av0.y);
        au.s[2] = f2bf(av0.z); au.s[3] = f2bf(av0.w);
        au.s[4] = f2bf(av1.x); au.s[5] = f2bf(av1.y);
        au.s[6] = f2bf(av1.z); au.s[7] = f2bf(av1.w);
        __syncthreads();
        #pragma unroll
        for (int nt = 0; nt < 8; ++nt) {
            bf16x8 bfrag = *(const bf16x8*)&Bs[(nt * 16 + ln15) * 20 + q * 4];
            acc[nt] = __builtin_amdgcn_mfma_f32_16x16x32_bf16(au.v, bfrag, acc[nt], 0, 0, 0);
        }
    }

    float wr[4];
    #pragma unroll
    for (int r = 0; r < 4; ++r) wr[r] = wls_s[(wv << 4) + q * 4 + r];
    const float* b1p = b1 + k * C_ + n0 + ln15;
    #pragma unroll
    for (int nt = 0; nt < 8; ++nt) {
        float bias = b1p[nt * 16];
        float partv = 0.f;
        #pragma unroll
        for (int r = 0; r < 4; ++r)
            partv += wr[r] * fmaxf(acc[nt][r] + bias, 0.f);
        atomicAdd(&hsum_s[nt * 16 + ln15], partv);
    }
    __syncthreads();
    if (tid < 128) atomicAdd(&hsum[(size_t)p * C_ + n0 + tid], hsum_s[tid]);
}

// combine partials: ctmp[b,k,e] += sum_{c in chunk} hsum[b,k,c] * w2[k,c,e]
__global__ __launch_bounds__(256) void k_comb(const float* __restrict__ hsum,
                                              const float* __restrict__ w2,
                                              float* __restrict__ ctmp) {
    int et = blockIdx.x, k = blockIdx.y, cc = blockIdx.z;
    int e0 = et * 64, c0 = cc * 128;
    __shared__ float hs[8][128];
    int t = threadIdx.x;
    for (int i = t; i < 1024; i += 256) {
        int b = i >> 7, c = i & 127;
        hs[b][c] = hsum[(size_t)((b * 8 + k) << 9) + c0 + c];
    }
    __syncthreads();
    int e = e0 + (t & 63); int g = t >> 6;
    float a0 = 0.f, a1 = 0.f;
    const float* w2p = w2 + (size_t)k * C_ * C_ + e;
    #pragma unroll 4
    for (int c = 0; c < 128; ++c) {
        float wv = w2p[(size_t)(c0 + c) * C_];
        a0 = fmaf(hs[g][c], wv, a0);
        a1 = fmaf(hs[g + 4][c], wv, a1);
    }
    atomicAdd(&ctmp[((g * 8 + k) << 9) + e], a0);
    atomicAdd(&ctmp[(((g + 4) * 8 + k) << 9) + e], a1);
}

// finalize: centers = (ctmp + b2*mass)/max(mass,eps); thread0 writes lb_loss
__global__ __launch_bounds__(256) void k_fin(const float* __restrict__ ctmp,
                                             const float* __restrict__ b2,
                                             const float* __restrict__ mass,
                                             const int* __restrict__ cnt,
                                             float* __restrict__ out) {
    int i = blockIdx.x * 256 + threadIdx.x;  // 0..32767
    int b = i >> 12; int ke = i & 4095; int k = ke >> 9;
    float m = mass[b * 8 + k];
    out[i] = (ctmp[i] + b2[ke] * m) / fmaxf(m, EPS);
    if (i == 0) {
        float u[8]; float s = 0.f;
        for (int kk = 0; kk < 8; ++kk) {
            int ck = 0;
            for (int bb = 0; bb < 8; ++bb) ck += cnt[bb * K_ + kk];
            u[kk] = (float)ck / (float)(B_ * N_);
            s += u[kk];
        }
        float mean = s / 8.f;
        float var = 0.f;
        for (int kk = 0; kk < 8; ++kk) { float d = u[kk] - mean; var += d * d; }
        var /= 8.f;
        float denom = mean + EPS;
        out[B_ * K_ * C_] = var / (denom * denom);
    }
}

extern "C" void kernel_launch(void* const* d_in, const int* in_sizes, int n_in,
                              void* d_out, int out_size, void* d_ws, size_t ws_size,
                              hipStream_t stream) {
    (void)in_sizes; (void)n_in; (void)out_size; (void)ws_size;
    const float* tokens   = (const float*)d_in[0];
    const float* geno_vec = (const float*)d_in[1];
    const float* gate_w   = (const float*)d_in[2];
    const float* gate_b   = (const float*)d_in[3];
    const float* geno_w   = (const float*)d_in[4];
    const float* geno_b   = (const float*)d_in[5];
    const float* w1       = (const float*)d_in[6];
    const float* b1       = (const float*)d_in[7];
    const float* w2       = (const float*)d_in[8];
    const float* b2       = (const float*)d_in[9];
    float* out = (float*)d_out;
    float* ws  = (float*)d_ws;

    float*  geno_out = ws;                       // 64
    int*    cnt      = (int*)(ws + 64);          // 64
    float*  mass     = ws + 128;                 // 64
    float*  hsum     = ws + 192;                 // 32768
    float*  ctmp     = ws + 32960;               // 32768
    float*  lw       = ws + 65728;               // 131072
    int*    ln       = (int*)(ws + 196800);      // 131072
    ushort* w1t      = (ushort*)(ws + 327872);   // 2097152 bf16 (4 MB)
    // tpi/tpw overlay the hsum/ctmp region; consumed by k_build BEFORE the
    // memset below zeroes it (stream order guarantees this).
    int*    tpi      = (int*)(ws + 192);                 // 16384 ints
    float2* tpw      = (float2*)(ws + 192 + 16384);      // 16384 float2

    k_geno<<<dim3(B_ * K_), dim3(64), 0, stream>>>(geno_vec, geno_w, geno_b, geno_out);
    k_gate<<<dim3(B_ * N_ / 4), dim3(256), 0, stream>>>(tokens, gate_w, gate_b, geno_out,
                                                        tpi, tpw);
    k_build<<<dim3(B_), dim3(1024), 0, stream>>>(tpi, tpw, cnt, mass, ln, lw);
    // zero hsum + ctmp (after tpi/tpw consumed)
    hipMemsetAsync(ws + 192, 0, (size_t)(2 * B_ * K_ * C_) * sizeof(float), stream);
    k_w1t<<<dim3(8, 8, K_), dim3(256), 0, stream>>>(w1, w1t);
    k_ffn1<<<dim3(N_ / 64, C_ / 128, B_ * K_), dim3(256), 0, stream>>>(tokens, w1t, b1,
                                                                       cnt, ln, lw, hsum);
    k_comb<<<dim3(8, K_, 4), dim3(256), 0, stream>>>(hsum, w2, ctmp);
    k_fin<<<dim3(128), dim3(256), 0, stream>>>(ctmp, b2, mass, cnt, out);
}

// Round 4
// 321.646 us; speedup vs baseline: 3.3857x; 1.1111x over previous
//
#include <hip/hip_runtime.h>
#include <math.h>

#define B_ 8
#define N_ 2048
#define C_ 512
#define K_ 8
#define EPS 1e-6f
#define GENO_RATIO 0.1f

typedef __bf16 bf16x8 __attribute__((ext_vector_type(8)));
typedef float f32x4 __attribute__((ext_vector_type(4)));

__device__ __forceinline__ ushort f2bf(float x) {
    unsigned int u = __float_as_uint(x);
    u += 0x7fffu + ((u >> 16) & 1u);   // RNE (inputs are finite)
    return (ushort)(u >> 16);
}

__device__ __forceinline__ bf16x8 as_bf(uint4 x) {
    union { uint4 u; bf16x8 b; } t; t.u = x; return t.b;
}

// ---------------------------------------------------------------------------
// ws layout (float element offsets):
// [0,64)               geno logits [B,K]
// [64,128)             cnt (int)   [B,K]
// [128,192)            mass        [B,K]
// [192,32960)          hsum        [B,K,C]   (tpi/tpw overlay before memset)
// [32960,65728)        ctmp        [B,K,C]
// [65728,196800)       lw          [B,K,N]
// [196800,327872)      ln (int)    [B,K,N]
// [327872,1376448)     w1t (bf16)  [K,C,C]   4 MB
// [1376448,5570752)    tb16 (bf16) [B,N,C]   16.8 MB   (total ~22.3 MB)
// ---------------------------------------------------------------------------

__global__ __launch_bounds__(64) void k_geno(const float* __restrict__ geno_vec,
                                             const float* __restrict__ geno_w,
                                             const float* __restrict__ geno_b,
                                             float* __restrict__ geno_out) {
    int p = blockIdx.x; int b = p >> 3; int k = p & 7;
    int lane = threadIdx.x;
    float acc = 0.f;
    #pragma unroll
    for (int i = 0; i < C_ / 64; ++i) {
        int c = lane + 64 * i;
        acc += geno_vec[b * C_ + c] * geno_w[c * K_ + k];
    }
    #pragma unroll
    for (int off = 32; off > 0; off >>= 1) acc += __shfl_xor(acc, off, 64);
    if (lane == 0) geno_out[p] = acc + geno_b[k];
}

// gating: one wave per token. fp32 GEMV + top-2 + softmax; also emits bf16
// copy of the token row (coalesced 2B stores). No atomics.
__global__ __launch_bounds__(256) void k_gate(const float* __restrict__ tokens,
                                              const float* __restrict__ gate_w,
                                              const float* __restrict__ gate_b,
                                              const float* __restrict__ geno_out,
                                              int* __restrict__ tpi,
                                              float2* __restrict__ tpw,
                                              ushort* __restrict__ tb16) {
    int wave = threadIdx.x >> 6;
    int lane = threadIdx.x & 63;
    int t = blockIdx.x * 4 + wave;
    int b = t >> 11;
    float acc[8] = {0.f,0.f,0.f,0.f,0.f,0.f,0.f,0.f};
    const float* trow = tokens + (size_t)t * C_;
    ushort* brow = tb16 + (size_t)t * C_;
    #pragma unroll
    for (int i = 0; i < C_ / 64; ++i) {
        int c = lane + 64 * i;
        float tv = trow[c];
        brow[c] = f2bf(tv);
        const float4* g4 = (const float4*)(gate_w + c * K_);
        float4 g0 = g4[0], g1 = g4[1];
        acc[0] = fmaf(tv, g0.x, acc[0]); acc[1] = fmaf(tv, g0.y, acc[1]);
        acc[2] = fmaf(tv, g0.z, acc[2]); acc[3] = fmaf(tv, g0.w, acc[3]);
        acc[4] = fmaf(tv, g1.x, acc[4]); acc[5] = fmaf(tv, g1.y, acc[5]);
        acc[6] = fmaf(tv, g1.z, acc[6]); acc[7] = fmaf(tv, g1.w, acc[7]);
    }
    #pragma unroll
    for (int off = 32; off > 0; off >>= 1) {
        #pragma unroll
        for (int j = 0; j < 8; ++j) acc[j] += __shfl_xor(acc[j], off, 64);
    }
    if (lane == 0) {
        float lg[8];
        #pragma unroll
        for (int j = 0; j < 8; ++j)
            lg[j] = acc[j] + gate_b[j] + GENO_RATIO * geno_out[b * K_ + j];
        int i0 = 0; float v0 = lg[0];
        #pragma unroll
        for (int j = 1; j < 8; ++j) if (lg[j] > v0) { v0 = lg[j]; i0 = j; }
        int i1 = -1; float v1 = -1e30f;
        #pragma unroll
        for (int j = 0; j < 8; ++j) if (j != i0 && lg[j] > v1) { v1 = lg[j]; i1 = j; }
        float e = expf(v1 - v0);
        float w0 = 1.f / (1.f + e);
        float w1 = e / (1.f + e);
        w0 = fmaxf(w0, EPS); w1 = fmaxf(w1, EPS);
        float s = w0 + w1; w0 /= s; w1 /= s;
        tpi[t] = i0 | (i1 << 4);
        tpw[t] = make_float2(w0, w1);
    }
}

// list build: one block per batch b; LDS counters only, zero global atomics.
__global__ __launch_bounds__(1024) void k_build(const int* __restrict__ tpi,
                                                const float2* __restrict__ tpw,
                                                int* __restrict__ cnt,
                                                float* __restrict__ mass,
                                                int* __restrict__ ln,
                                                float* __restrict__ lw) {
    int b = blockIdx.x;
    __shared__ int   lcnt[8];
    __shared__ float lmass[8];
    int tid = threadIdx.x;
    if (tid < 8) { lcnt[tid] = 0; lmass[tid] = 0.f; }
    __syncthreads();
    for (int n = tid; n < N_; n += 1024) {
        int pk = tpi[b * N_ + n];
        float2 w = tpw[b * N_ + n];
        int i0 = pk & 15, i1 = pk >> 4;
        int pos0 = atomicAdd(&lcnt[i0], 1);
        ln[(b * 8 + i0) * N_ + pos0] = n;
        lw[(b * 8 + i0) * N_ + pos0] = w.x;
        atomicAdd(&lmass[i0], w.x);
        int pos1 = atomicAdd(&lcnt[i1], 1);
        ln[(b * 8 + i1) * N_ + pos1] = n;
        lw[(b * 8 + i1) * N_ + pos1] = w.y;
        atomicAdd(&lmass[i1], w.y);
    }
    __syncthreads();
    if (tid < 8) {
        cnt[b * 8 + tid]  = lcnt[tid];
        mass[b * 8 + tid] = lmass[tid];
    }
}

// transpose + convert: w1t[k][n][c] (bf16) = w1[k][c][n]
__global__ __launch_bounds__(256) void k_w1t(const float* __restrict__ w1,
                                             ushort* __restrict__ w1t) {
    int k = blockIdx.z; int c0 = blockIdx.x * 64; int n0 = blockIdx.y * 64;
    __shared__ float tile[64][65];
    int t = threadIdx.x;
    int tr = t >> 4;          // 0..15
    int tc4 = (t & 15) * 4;   // 0..60
    const float* src = w1 + (size_t)k * C_ * C_;
    #pragma unroll
    for (int i = 0; i < 4; ++i) {
        int c = c0 + tr + i * 16;
        float4 v = *(const float4*)(src + (size_t)c * C_ + n0 + tc4);
        tile[tr + i * 16][tc4 + 0] = v.x; tile[tr + i * 16][tc4 + 1] = v.y;
        tile[tr + i * 16][tc4 + 2] = v.z; tile[tr + i * 16][tc4 + 3] = v.w;
    }
    __syncthreads();
    ushort* dst = w1t + (size_t)k * C_ * C_;
    #pragma unroll
    for (int i = 0; i < 4; ++i) {
        int rr = tr + i * 16;
        int n = n0 + rr;
        uint2 o;
        o.x = (unsigned)f2bf(tile[tc4 + 0][rr]) | ((unsigned)f2bf(tile[tc4 + 1][rr]) << 16);
        o.y = (unsigned)f2bf(tile[tc4 + 2][rr]) | ((unsigned)f2bf(tile[tc4 + 3][rr]) << 16);
        *(uint2*)(dst + (size_t)n * C_ + c0 + tc4) = o;
    }
}

// grouped GEMM1, MFMA bf16, NO LDS staging: per-lane global loads ARE the
// fragments. Block = 4 waves, tile 64 tokens x 512 ch (wave owns 128 ch).
// Double-buffered fragment prefetch; no barriers in the K-loop.
__global__ __launch_bounds__(256, 2) void k_ffn1(const ushort* __restrict__ tb16,
                                                 const ushort* __restrict__ w1t,
                                                 const float* __restrict__ b1,
                                                 const int* __restrict__ cnt,
                                                 const int* __restrict__ ln,
                                                 const float* __restrict__ lw,
                                                 float* __restrict__ hsum) {
    int p = blockIdx.y; int b = p >> 3; int k = p & 7;
    int count = cnt[p];
    int m0 = blockIdx.x * 64;
    if (m0 >= count) return;

    __shared__ int   ns_s[64];
    __shared__ float wls_s[64];
    int tid = threadIdx.x;
    if (tid < 64) {
        int mi = m0 + tid;
        bool v = mi < count;
        ns_s[tid]  = v ? ln[p * N_ + mi] : 0;
        wls_s[tid] = v ? lw[p * N_ + mi] : 0.f;
    }
    __syncthreads();

    int wv = tid >> 6, lane = tid & 63;
    int ln15 = lane & 15, q = lane >> 4;

    const ushort* ap[4];
    #pragma unroll
    for (int mt = 0; mt < 4; ++mt)
        ap[mt] = tb16 + ((size_t)(b * N_ + ns_s[mt * 16 + ln15])) * C_ + q * 8;
    const ushort* w1k = w1t + (size_t)k * C_ * C_;
    const ushort* bp[8];
    #pragma unroll
    for (int j = 0; j < 8; ++j)
        bp[j] = w1k + (size_t)(wv * 128 + j * 16 + ln15) * C_ + q * 8;

    f32x4 acc[4][8];
    #pragma unroll
    for (int mt = 0; mt < 4; ++mt)
        #pragma unroll
        for (int j = 0; j < 8; ++j) acc[mt][j] = (f32x4){0.f, 0.f, 0.f, 0.f};

    uint4 a_cur[4], b_cur[8], a_nxt[4], b_nxt[8];
    #pragma unroll
    for (int mt = 0; mt < 4; ++mt) a_cur[mt] = *(const uint4*)(ap[mt]);
    #pragma unroll
    for (int j = 0; j < 8; ++j)  b_cur[j] = *(const uint4*)(bp[j]);

    #pragma unroll
    for (int it = 0; it < 16; ++it) {
        if (it < 15) {
            int cc = (it + 1) * 32;
            #pragma unroll
            for (int mt = 0; mt < 4; ++mt) a_nxt[mt] = *(const uint4*)(ap[mt] + cc);
            #pragma unroll
            for (int j = 0; j < 8; ++j)  b_nxt[j] = *(const uint4*)(bp[j] + cc);
        }
        #pragma unroll
        for (int mt = 0; mt < 4; ++mt)
            #pragma unroll
            for (int j = 0; j < 8; ++j)
                acc[mt][j] = __builtin_amdgcn_mfma_f32_16x16x32_bf16(
                    as_bf(a_cur[mt]), as_bf(b_cur[j]), acc[mt][j], 0, 0, 0);
        #pragma unroll
        for (int mt = 0; mt < 4; ++mt) a_cur[mt] = a_nxt[mt];
        #pragma unroll
        for (int j = 0; j < 8; ++j)  b_cur[j] = b_nxt[j];
    }

    // epilogue: bias+relu+gate-weight; reduce 4 q-lanes; 1 atomic per column
    float wrow[4][4];
    #pragma unroll
    for (int mt = 0; mt < 4; ++mt)
        #pragma unroll
        for (int r = 0; r < 4; ++r) wrow[mt][r] = wls_s[mt * 16 + q * 4 + r];
    const float* b1k = b1 + k * C_;
    float* hp = hsum + (size_t)p * C_;
    #pragma unroll
    for (int j = 0; j < 8; ++j) {
        int n = wv * 128 + j * 16 + ln15;
        float bias = b1k[n];
        float s = 0.f;
        #pragma unroll
        for (int mt = 0; mt < 4; ++mt)
            #pragma unroll
            for (int r = 0; r < 4; ++r)
                s += wrow[mt][r] * fmaxf(acc[mt][j][r] + bias, 0.f);
        s += __shfl_xor(s, 16, 64);
        s += __shfl_xor(s, 32, 64);
        if (q == 0) atomicAdd(&hp[n], s);
    }
}

// combine partials: ctmp[b,k,e] += sum_{c in chunk} hsum[b,k,c] * w2[k,c,e]
__global__ __launch_bounds__(256) void k_comb(const float* __restrict__ hsum,
                                              const float* __restrict__ w2,
                                              float* __restrict__ ctmp) {
    int et = blockIdx.x, k = blockIdx.y, cc = blockIdx.z;
    int e0 = et * 64, c0 = cc * 128;
    __shared__ float hs[8][128];
    int t = threadIdx.x;
    for (int i = t; i < 1024; i += 256) {
        int b = i >> 7, c = i & 127;
        hs[b][c] = hsum[(size_t)((b * 8 + k) << 9) + c0 + c];
    }
    __syncthreads();
    int e = e0 + (t & 63); int g = t >> 6;
    float a0 = 0.f, a1 = 0.f;
    const float* w2p = w2 + (size_t)k * C_ * C_ + e;
    #pragma unroll 4
    for (int c = 0; c < 128; ++c) {
        float wv = w2p[(size_t)(c0 + c) * C_];
        a0 = fmaf(hs[g][c], wv, a0);
        a1 = fmaf(hs[g + 4][c], wv, a1);
    }
    atomicAdd(&ctmp[((g * 8 + k) << 9) + e], a0);
    atomicAdd(&ctmp[(((g + 4) * 8 + k) << 9) + e], a1);
}

// finalize: centers = (ctmp + b2*mass)/max(mass,eps); thread0 writes lb_loss
__global__ __launch_bounds__(256) void k_fin(const float* __restrict__ ctmp,
                                             const float* __restrict__ b2,
                                             const float* __restrict__ mass,
                                             const int* __restrict__ cnt,
                                             float* __restrict__ out) {
    int i = blockIdx.x * 256 + threadIdx.x;  // 0..32767
    int b = i >> 12; int ke = i & 4095; int k = ke >> 9;
    float m = mass[b * 8 + k];
    out[i] = (ctmp[i] + b2[ke] * m) / fmaxf(m, EPS);
    if (i == 0) {
        float u[8]; float s = 0.f;
        for (int kk = 0; kk < 8; ++kk) {
            int ck = 0;
            for (int bb = 0; bb < 8; ++bb) ck += cnt[bb * K_ + kk];
            u[kk] = (float)ck / (float)(B_ * N_);
            s += u[kk];
        }
        float mean = s / 8.f;
        float var = 0.f;
        for (int kk = 0; kk < 8; ++kk) { float d = u[kk] - mean; var += d * d; }
        var /= 8.f;
        float denom = mean + EPS;
        out[B_ * K_ * C_] = var / (denom * denom);
    }
}

extern "C" void kernel_launch(void* const* d_in, const int* in_sizes, int n_in,
                              void* d_out, int out_size, void* d_ws, size_t ws_size,
                              hipStream_t stream) {
    (void)in_sizes; (void)n_in; (void)out_size; (void)ws_size;
    const float* tokens   = (const float*)d_in[0];
    const float* geno_vec = (const float*)d_in[1];
    const float* gate_w   = (const float*)d_in[2];
    const float* gate_b   = (const float*)d_in[3];
    const float* geno_w   = (const float*)d_in[4];
    const float* geno_b   = (const float*)d_in[5];
    const float* w1       = (const float*)d_in[6];
    const float* b1       = (const float*)d_in[7];
    const float* w2       = (const float*)d_in[8];
    const float* b2       = (const float*)d_in[9];
    float* out = (float*)d_out;
    float* ws  = (float*)d_ws;

    float*  geno_out = ws;                       // 64
    int*    cnt      = (int*)(ws + 64);          // 64
    float*  mass     = ws + 128;                 // 64
    float*  hsum     = ws + 192;                 // 32768
    float*  ctmp     = ws + 32960;               // 32768
    float*  lw       = ws + 65728;               // 131072
    int*    ln       = (int*)(ws + 196800);      // 131072
    ushort* w1t      = (ushort*)(ws + 327872);   // 2,097,152 bf16 (4 MB)
    ushort* tb16     = (ushort*)(ws + 1376448);  // 8,388,608 bf16 (16.8 MB)
    // tpi/tpw overlay hsum/ctmp; consumed by k_build BEFORE the memset below.
    int*    tpi      = (int*)(ws + 192);                 // 16384 ints
    float2* tpw      = (float2*)(ws + 192 + 16384);      // 16384 float2

    k_geno<<<dim3(B_ * K_), dim3(64), 0, stream>>>(geno_vec, geno_w, geno_b, geno_out);
    k_gate<<<dim3(B_ * N_ / 4), dim3(256), 0, stream>>>(tokens, gate_w, gate_b, geno_out,
                                                        tpi, tpw, tb16);
    k_build<<<dim3(B_), dim3(1024), 0, stream>>>(tpi, tpw, cnt, mass, ln, lw);
    // zero hsum + ctmp (after tpi/tpw consumed)
    hipMemsetAsync(ws + 192, 0, (size_t)(2 * B_ * K_ * C_) * sizeof(float), stream);
    k_w1t<<<dim3(8, 8, K_), dim3(256), 0, stream>>>(w1, w1t);
    k_ffn1<<<dim3(N_ / 64, B_ * K_), dim3(256), 0, stream>>>(tb16, w1t, b1,
                                                             cnt, ln, lw, hsum);
    k_comb<<<dim3(8, K_, 4), dim3(256), 0, stream>>>(hsum, w2, ctmp);
    k_fin<<<dim3(128), dim3(256), 0, stream>>>(ctmp, b2, mass, cnt, out);
}

// Round 5
// 228.330 us; speedup vs baseline: 4.7694x; 1.4087x over previous
//
#include <hip/hip_runtime.h>
#include <math.h>

#define B_ 8
#define N_ 2048
#define C_ 512
#define K_ 8
#define EPS 1e-6f
#define GENO_RATIO 0.1f

typedef __bf16 bf16x8 __attribute__((ext_vector_type(8)));
typedef float f32x4 __attribute__((ext_vector_type(4)));

__device__ __forceinline__ ushort f2bf(float x) {
    unsigned int u = __float_as_uint(x);
    u += 0x7fffu + ((u >> 16) & 1u);   // RNE (inputs are finite)
    return (ushort)(u >> 16);
}

__device__ __forceinline__ bf16x8 as_bf(uint4 x) {
    union { uint4 u; bf16x8 b; } t; t.u = x; return t.b;
}

// ---------------------------------------------------------------------------
// ws layout (float element offsets):
// [0,64)               geno logits [B,K]
// [64,128)             cnt (int)   [B,K]
// [128,192)            mass        [B,K]
// [192,32960)          hsum        [B,K,C]   (tpi/tpw overlay before memset)
// [32960,65728)        ctmp        [B,K,C]
// [65728,196800)       lw          [B,K,N]
// [196800,327872)      ln (int)    [B,K,N]
// [327872,1376448)     w1t2 (bf16) [K][16 cb][512 n][32 cc]   4 MB  (K-tiled)
// [1376448,5570752)    tb2  (bf16) [B][16 cb][2048 n][32 cc]  16.8 MB
// ---------------------------------------------------------------------------

__global__ __launch_bounds__(64) void k_geno(const float* __restrict__ geno_vec,
                                             const float* __restrict__ geno_w,
                                             const float* __restrict__ geno_b,
                                             float* __restrict__ geno_out) {
    int p = blockIdx.x; int b = p >> 3; int k = p & 7;
    int lane = threadIdx.x;
    float acc = 0.f;
    #pragma unroll
    for (int i = 0; i < C_ / 64; ++i) {
        int c = lane + 64 * i;
        acc += geno_vec[b * C_ + c] * geno_w[c * K_ + k];
    }
    #pragma unroll
    for (int off = 32; off > 0; off >>= 1) acc += __shfl_xor(acc, off, 64);
    if (lane == 0) geno_out[p] = acc + geno_b[k];
}

// gating: one wave per token. fp32 GEMV + top-2 + softmax; also emits the
// K-chunk-tiled bf16 copy of the token row. No atomics.
__global__ __launch_bounds__(256) void k_gate(const float* __restrict__ tokens,
                                              const float* __restrict__ gate_w,
                                              const float* __restrict__ gate_b,
                                              const float* __restrict__ geno_out,
                                              int* __restrict__ tpi,
                                              float2* __restrict__ tpw,
                                              ushort* __restrict__ tb2) {
    int wave = threadIdx.x >> 6;
    int lane = threadIdx.x & 63;
    int t = blockIdx.x * 4 + wave;
    int b = t >> 11;
    int n = t & 2047;
    float acc[8] = {0.f,0.f,0.f,0.f,0.f,0.f,0.f,0.f};
    const float* trow = tokens + (size_t)t * C_;
    #pragma unroll
    for (int i = 0; i < C_ / 64; ++i) {
        int c = lane + 64 * i;
        float tv = trow[c];
        int cb = c >> 5, cc = c & 31;
        tb2[((size_t)(b * 16 + cb) * 2048 + n) * 32 + cc] = f2bf(tv);
        const float4* g4 = (const float4*)(gate_w + c * K_);
        float4 g0 = g4[0], g1 = g4[1];
        acc[0] = fmaf(tv, g0.x, acc[0]); acc[1] = fmaf(tv, g0.y, acc[1]);
        acc[2] = fmaf(tv, g0.z, acc[2]); acc[3] = fmaf(tv, g0.w, acc[3]);
        acc[4] = fmaf(tv, g1.x, acc[4]); acc[5] = fmaf(tv, g1.y, acc[5]);
        acc[6] = fmaf(tv, g1.z, acc[6]); acc[7] = fmaf(tv, g1.w, acc[7]);
    }
    #pragma unroll
    for (int off = 32; off > 0; off >>= 1) {
        #pragma unroll
        for (int j = 0; j < 8; ++j) acc[j] += __shfl_xor(acc[j], off, 64);
    }
    if (lane == 0) {
        float lg[8];
        #pragma unroll
        for (int j = 0; j < 8; ++j)
            lg[j] = acc[j] + gate_b[j] + GENO_RATIO * geno_out[b * K_ + j];
        int i0 = 0; float v0 = lg[0];
        #pragma unroll
        for (int j = 1; j < 8; ++j) if (lg[j] > v0) { v0 = lg[j]; i0 = j; }
        int i1 = -1; float v1 = -1e30f;
        #pragma unroll
        for (int j = 0; j < 8; ++j) if (j != i0 && lg[j] > v1) { v1 = lg[j]; i1 = j; }
        float e = expf(v1 - v0);
        float w0 = 1.f / (1.f + e);
        float w1 = e / (1.f + e);
        w0 = fmaxf(w0, EPS); w1 = fmaxf(w1, EPS);
        float s = w0 + w1; w0 /= s; w1 /= s;
        tpi[t] = i0 | (i1 << 4);
        tpw[t] = make_float2(w0, w1);
    }
}

// list build: one block per batch b; LDS counters only, zero global atomics.
__global__ __launch_bounds__(1024) void k_build(const int* __restrict__ tpi,
                                                const float2* __restrict__ tpw,
                                                int* __restrict__ cnt,
                                                float* __restrict__ mass,
                                                int* __restrict__ ln,
                                                float* __restrict__ lw) {
    int b = blockIdx.x;
    __shared__ int   lcnt[8];
    __shared__ float lmass[8];
    int tid = threadIdx.x;
    if (tid < 8) { lcnt[tid] = 0; lmass[tid] = 0.f; }
    __syncthreads();
    for (int n = tid; n < N_; n += 1024) {
        int pk = tpi[b * N_ + n];
        float2 w = tpw[b * N_ + n];
        int i0 = pk & 15, i1 = pk >> 4;
        int pos0 = atomicAdd(&lcnt[i0], 1);
        ln[(b * 8 + i0) * N_ + pos0] = n;
        lw[(b * 8 + i0) * N_ + pos0] = w.x;
        atomicAdd(&lmass[i0], w.x);
        int pos1 = atomicAdd(&lcnt[i1], 1);
        ln[(b * 8 + i1) * N_ + pos1] = n;
        lw[(b * 8 + i1) * N_ + pos1] = w.y;
        atomicAdd(&lmass[i1], w.y);
    }
    __syncthreads();
    if (tid < 8) {
        cnt[b * 8 + tid]  = lcnt[tid];
        mass[b * 8 + tid] = lmass[tid];
    }
}

// transpose + convert into K-chunk-tiled layout:
// w1t2[k][cb][n][cc] = bf16(w1[k][cb*32+cc][n])
__global__ __launch_bounds__(256) void k_w1t(const float* __restrict__ w1,
                                             ushort* __restrict__ w1t2) {
    int k = blockIdx.z; int c0 = blockIdx.x * 64; int n0 = blockIdx.y * 64;
    __shared__ float tile[64][65];
    int t = threadIdx.x;
    int tr = t >> 4;          // 0..15
    int tc4 = (t & 15) * 4;   // 0..60
    const float* src = w1 + (size_t)k * C_ * C_;
    #pragma unroll
    for (int i = 0; i < 4; ++i) {
        int c = c0 + tr + i * 16;
        float4 v = *(const float4*)(src + (size_t)c * C_ + n0 + tc4);
        tile[tr + i * 16][tc4 + 0] = v.x; tile[tr + i * 16][tc4 + 1] = v.y;
        tile[tr + i * 16][tc4 + 2] = v.z; tile[tr + i * 16][tc4 + 3] = v.w;
    }
    __syncthreads();
    #pragma unroll
    for (int i = 0; i < 4; ++i) {
        int rr = tr + i * 16;        // n - n0
        int n = n0 + rr;
        int c = c0 + tc4;            // 4 consecutive c, within one 32-chunk
        int cb = c >> 5, cc = c & 31;
        uint2 o;
        o.x = (unsigned)f2bf(tile[tc4 + 0][rr]) | ((unsigned)f2bf(tile[tc4 + 1][rr]) << 16);
        o.y = (unsigned)f2bf(tile[tc4 + 2][rr]) | ((unsigned)f2bf(tile[tc4 + 3][rr]) << 16);
        *(uint2*)(w1t2 + ((size_t)(k * 16 + cb) * 512 + n) * 32 + cc) = o;
    }
}

// grouped GEMM1, MFMA bf16. B-fragments: direct coalesced global loads from
// the K-tiled w1t2 (1 KB contiguous per wave-instr), double-buffered in VGPRs.
// A: gathered token rows staged once per block into padded LDS (dbuf,
// conflict-free, 1 barrier/iter). Epilogue: bias+relu+gate-weight -> hsum.
__global__ __launch_bounds__(256) void k_ffn1(const ushort* __restrict__ tb2,
                                              const ushort* __restrict__ w1t2,
                                              const float* __restrict__ b1,
                                              const int* __restrict__ cnt,
                                              const int* __restrict__ ln,
                                              const float* __restrict__ lw,
                                              float* __restrict__ hsum) {
    int p = blockIdx.y; int b = p >> 3; int k = p & 7;
    int count = cnt[p];
    int m0 = blockIdx.x * 64;
    if (m0 >= count) return;

    __shared__ ushort As[2][64 * 36];   // 64 rows x 32 bf16, stride 36 ushorts (72B)
    __shared__ int   ns_s[64];
    __shared__ float wls_s[64];

    int tid = threadIdx.x;
    if (tid < 64) {
        int mi = m0 + tid;
        bool v = mi < count;
        ns_s[tid]  = v ? ln[p * N_ + mi] : 0;
        wls_s[tid] = v ? lw[p * N_ + mi] : 0.f;
    }
    __syncthreads();

    int wv = tid >> 6, lane = tid & 63;
    int ln15 = lane & 15, q = lane >> 4;

    // A staging: thread t handles row r=t>>2, 16B piece q4=t&3
    int r = tid >> 2, q4 = tid & 3;
    const ushort* agbase = tb2 + ((size_t)(b * 16) * 2048 + ns_s[r]) * 32 + q4 * 8;
    ushort* awr = &As[0][r * 36 + q4 * 8];   // buffer 0 addr; buffer1 = +64*36

    // B: per-wave coalesced fragment loads; frag j at chunk cb:
    //   bbase + cb*16384 + j*512  (ushort units)
    const ushort* bbase = w1t2 + ((size_t)(k * 16) * 512 + wv * 128 + ln15) * 32 + q * 8;

    f32x4 acc[4][8];
    #pragma unroll
    for (int mt = 0; mt < 4; ++mt)
        #pragma unroll
        for (int j = 0; j < 8; ++j) acc[mt][j] = (f32x4){0.f, 0.f, 0.f, 0.f};

    // prologue: stage A chunk 0, load B chunk 0
    uint4 b_cur[8], b_nxt[8];
    {
        uint4 av = *(const uint4*)(agbase);
        *(uint4*)awr = av;
    }
    #pragma unroll
    for (int j = 0; j < 8; ++j) b_cur[j] = *(const uint4*)(bbase + j * 512);
    __syncthreads();

    const ushort* ards = &As[0][0];
    #pragma unroll
    for (int cb = 0; cb < 16; ++cb) {
        uint4 av;
        if (cb < 15) {
            av = *(const uint4*)(agbase + (size_t)(cb + 1) * 2048 * 32);
            #pragma unroll
            for (int j = 0; j < 8; ++j)
                b_nxt[j] = *(const uint4*)(bbase + (size_t)(cb + 1) * 16384 + j * 512);
        }
        // A fragments from LDS (conflict-free: stride 18 dwords)
        bf16x8 afrag[4];
        const ushort* ab = ards + ((cb & 1) ? 64 * 36 : 0);
        #pragma unroll
        for (int mt = 0; mt < 4; ++mt)
            afrag[mt] = *(const bf16x8*)(ab + (mt * 16 + ln15) * 36 + q * 8);
        #pragma unroll
        for (int mt = 0; mt < 4; ++mt)
            #pragma unroll
            for (int j = 0; j < 8; ++j)
                acc[mt][j] = __builtin_amdgcn_mfma_f32_16x16x32_bf16(
                    afrag[mt], as_bf(b_cur[j]), acc[mt][j], 0, 0, 0);
        if (cb < 15) {
            *(uint4*)(awr + (((cb + 1) & 1) ? 64 * 36 : 0)) = av;
            #pragma unroll
            for (int j = 0; j < 8; ++j) b_cur[j] = b_nxt[j];
        }
        __syncthreads();
    }

    // epilogue: bias+relu+gate-weight; reduce 4 q-lanes; 1 atomic per column
    float wrow[4][4];
    #pragma unroll
    for (int mt = 0; mt < 4; ++mt)
        #pragma unroll
        for (int rr = 0; rr < 4; ++rr) wrow[mt][rr] = wls_s[mt * 16 + q * 4 + rr];
    const float* b1k = b1 + k * C_;
    float* hp = hsum + (size_t)p * C_;
    #pragma unroll
    for (int j = 0; j < 8; ++j) {
        int n = wv * 128 + j * 16 + ln15;
        float bias = b1k[n];
        float s = 0.f;
        #pragma unroll
        for (int mt = 0; mt < 4; ++mt)
            #pragma unroll
            for (int rr = 0; rr < 4; ++rr)
                s += wrow[mt][rr] * fmaxf(acc[mt][j][rr] + bias, 0.f);
        s += __shfl_xor(s, 16, 64);
        s += __shfl_xor(s, 32, 64);
        if (q == 0) atomicAdd(&hp[n], s);
    }
}

// combine partials: ctmp[b,k,e] += sum_{c in chunk} hsum[b,k,c] * w2[k,c,e]
__global__ __launch_bounds__(256) void k_comb(const float* __restrict__ hsum,
                                              const float* __restrict__ w2,
                                              float* __restrict__ ctmp) {
    int et = blockIdx.x, k = blockIdx.y, cc = blockIdx.z;
    int e0 = et * 64, c0 = cc * 128;
    __shared__ float hs[8][128];
    int t = threadIdx.x;
    for (int i = t; i < 1024; i += 256) {
        int b = i >> 7, c = i & 127;
        hs[b][c] = hsum[(size_t)((b * 8 + k) << 9) + c0 + c];
    }
    __syncthreads();
    int e = e0 + (t & 63); int g = t >> 6;
    float a0 = 0.f, a1 = 0.f;
    const float* w2p = w2 + (size_t)k * C_ * C_ + e;
    #pragma unroll 4
    for (int c = 0; c < 128; ++c) {
        float wv = w2p[(size_t)(c0 + c) * C_];
        a0 = fmaf(hs[g][c], wv, a0);
        a1 = fmaf(hs[g + 4][c], wv, a1);
    }
    atomicAdd(&ctmp[((g * 8 + k) << 9) + e], a0);
    atomicAdd(&ctmp[(((g + 4) * 8 + k) << 9) + e], a1);
}

// finalize: centers = (ctmp + b2*mass)/max(mass,eps); thread0 writes lb_loss
__global__ __launch_bounds__(256) void k_fin(const float* __restrict__ ctmp,
                                             const float* __restrict__ b2,
                                             const float* __restrict__ mass,
                                             const int* __restrict__ cnt,
                                             float* __restrict__ out) {
    int i = blockIdx.x * 256 + threadIdx.x;  // 0..32767
    int b = i >> 12; int ke = i & 4095; int k = ke >> 9;
    float m = mass[b * 8 + k];
    out[i] = (ctmp[i] + b2[ke] * m) / fmaxf(m, EPS);
    if (i == 0) {
        float u[8]; float s = 0.f;
        for (int kk = 0; kk < 8; ++kk) {
            int ck = 0;
            for (int bb = 0; bb < 8; ++bb) ck += cnt[bb * K_ + kk];
            u[kk] = (float)ck / (float)(B_ * N_);
            s += u[kk];
        }
        float mean = s / 8.f;
        float var = 0.f;
        for (int kk = 0; kk < 8; ++kk) { float d = u[kk] - mean; var += d * d; }
        var /= 8.f;
        float denom = mean + EPS;
        out[B_ * K_ * C_] = var / (denom * denom);
    }
}

extern "C" void kernel_launch(void* const* d_in, const int* in_sizes, int n_in,
                              void* d_out, int out_size, void* d_ws, size_t ws_size,
                              hipStream_t stream) {
    (void)in_sizes; (void)n_in; (void)out_size; (void)ws_size;
    const float* tokens   = (const float*)d_in[0];
    const float* geno_vec = (const float*)d_in[1];
    const float* gate_w   = (const float*)d_in[2];
    const float* gate_b   = (const float*)d_in[3];
    const float* geno_w   = (const float*)d_in[4];
    const float* geno_b   = (const float*)d_in[5];
    const float* w1       = (const float*)d_in[6];
    const float* b1       = (const float*)d_in[7];
    const float* w2       = (const float*)d_in[8];
    const float* b2       = (const float*)d_in[9];
    float* out = (float*)d_out;
    float* ws  = (float*)d_ws;

    float*  geno_out = ws;                       // 64
    int*    cnt      = (int*)(ws + 64);          // 64
    float*  mass     = ws + 128;                 // 64
    float*  hsum     = ws + 192;                 // 32768
    float*  ctmp     = ws + 32960;               // 32768
    float*  lw       = ws + 65728;               // 131072
    int*    ln       = (int*)(ws + 196800);      // 131072
    ushort* w1t2     = (ushort*)(ws + 327872);   // 2,097,152 bf16 (4 MB)
    ushort* tb2      = (ushort*)(ws + 1376448);  // 8,388,608 bf16 (16.8 MB)
    // tpi/tpw overlay hsum/ctmp; consumed by k_build BEFORE the memset below.
    int*    tpi      = (int*)(ws + 192);                 // 16384 ints
    float2* tpw      = (float2*)(ws + 192 + 16384);      // 16384 float2

    k_geno<<<dim3(B_ * K_), dim3(64), 0, stream>>>(geno_vec, geno_w, geno_b, geno_out);
    k_gate<<<dim3(B_ * N_ / 4), dim3(256), 0, stream>>>(tokens, gate_w, gate_b, geno_out,
                                                        tpi, tpw, tb2);
    k_build<<<dim3(B_), dim3(1024), 0, stream>>>(tpi, tpw, cnt, mass, ln, lw);
    // zero hsum + ctmp (after tpi/tpw consumed)
    hipMemsetAsync(ws + 192, 0, (size_t)(2 * B_ * K_ * C_) * sizeof(float), stream);
    k_w1t<<<dim3(8, 8, K_), dim3(256), 0, stream>>>(w1, w1t2);
    k_ffn1<<<dim3(N_ / 64, B_ * K_), dim3(256), 0, stream>>>(tb2, w1t2, b1,
                                                             cnt, ln, lw, hsum);
    k_comb<<<dim3(8, K_, 4), dim3(256), 0, stream>>>(hsum, w2, ctmp);
    k_fin<<<dim3(128), dim3(256), 0, stream>>>(ctmp, b2, mass, cnt, out);
}

// Round 6
// 213.125 us; speedup vs baseline: 5.1096x; 1.0713x over previous
//
#include <hip/hip_runtime.h>
#include <math.h>

#define B_ 8
#define N_ 2048
#define C_ 512
#define K_ 8
#define EPS 1e-6f
#define GENO_RATIO 0.1f

typedef __bf16 bf16x8 __attribute__((ext_vector_type(8)));
typedef float f32x4 __attribute__((ext_vector_type(4)));

__device__ __forceinline__ ushort f2bf(float x) {
    unsigned int u = __float_as_uint(x);
    u += 0x7fffu + ((u >> 16) & 1u);   // RNE (inputs are finite)
    return (ushort)(u >> 16);
}

__device__ __forceinline__ bf16x8 as_bf(uint4 x) {
    union { uint4 u; bf16x8 b; } t; t.u = x; return t.b;
}

// ---------------------------------------------------------------------------
// ws layout (float element offsets):
// [0,64)               geno logits [B,K]
// [64,128)             cnt (int)   [B,K]
// [128,192)            mass        [B,K]
// [192,32960)          hsum        [B,K,C]   (tpi/tpw overlay before memset)
// [32960,65728)        ctmp        [B,K,C]
// [65728,196800)       lw          [B,K,N]
// [196800,327872)      ln (int)    [B,K,N]
// [327872,1376448)     w1t2 (bf16) [K][16 cb][512 n][32 cc]   4 MB  (K-tiled)
// [1376448,5570752)    tb2  (bf16) [B][16 cb][2048 n][32 cc]  16.8 MB
// ---------------------------------------------------------------------------

__global__ __launch_bounds__(64) void k_geno(const float* __restrict__ geno_vec,
                                             const float* __restrict__ geno_w,
                                             const float* __restrict__ geno_b,
                                             float* __restrict__ geno_out) {
    int p = blockIdx.x; int b = p >> 3; int k = p & 7;
    int lane = threadIdx.x;
    float acc = 0.f;
    #pragma unroll
    for (int i = 0; i < C_ / 64; ++i) {
        int c = lane + 64 * i;
        acc += geno_vec[b * C_ + c] * geno_w[c * K_ + k];
    }
    #pragma unroll
    for (int off = 32; off > 0; off >>= 1) acc += __shfl_xor(acc, off, 64);
    if (lane == 0) geno_out[p] = acc + geno_b[k];
}

// gating: one wave per token; lane owns 8 contiguous channels.
// 2x float4 token loads, 1x uint4 bf16 store, butterfly-reduced logits.
__global__ __launch_bounds__(256) void k_gate(const float* __restrict__ tokens,
                                              const float* __restrict__ gate_w,
                                              const float* __restrict__ gate_b,
                                              const float* __restrict__ geno_out,
                                              int* __restrict__ tpi,
                                              float2* __restrict__ tpw,
                                              ushort* __restrict__ tb2) {
    int wave = threadIdx.x >> 6;
    int lane = threadIdx.x & 63;
    int t = blockIdx.x * 4 + wave;
    int b = t >> 11;
    int n = t & 2047;
    const float* trow = tokens + (size_t)t * C_;
    int c0 = lane * 8;
    float4 v0 = *(const float4*)(trow + c0);
    float4 v1 = *(const float4*)(trow + c0 + 4);
    float tv[8] = {v0.x, v0.y, v0.z, v0.w, v1.x, v1.y, v1.z, v1.w};

    float acc[8] = {0.f,0.f,0.f,0.f,0.f,0.f,0.f,0.f};
    #pragma unroll
    for (int i = 0; i < 8; ++i) {
        const float4* g4 = (const float4*)(gate_w + (size_t)(c0 + i) * K_);
        float4 g0 = g4[0], g1 = g4[1];
        acc[0] = fmaf(tv[i], g0.x, acc[0]); acc[1] = fmaf(tv[i], g0.y, acc[1]);
        acc[2] = fmaf(tv[i], g0.z, acc[2]); acc[3] = fmaf(tv[i], g0.w, acc[3]);
        acc[4] = fmaf(tv[i], g1.x, acc[4]); acc[5] = fmaf(tv[i], g1.y, acc[5]);
        acc[6] = fmaf(tv[i], g1.z, acc[6]); acc[7] = fmaf(tv[i], g1.w, acc[7]);
    }
    // bf16 pack + tiled store (8 channels of one 32-chunk -> 16B contiguous)
    {
        int cb = c0 >> 5, cc = c0 & 31;
        uint4 o;
        o.x = (unsigned)f2bf(tv[0]) | ((unsigned)f2bf(tv[1]) << 16);
        o.y = (unsigned)f2bf(tv[2]) | ((unsigned)f2bf(tv[3]) << 16);
        o.z = (unsigned)f2bf(tv[4]) | ((unsigned)f2bf(tv[5]) << 16);
        o.w = (unsigned)f2bf(tv[6]) | ((unsigned)f2bf(tv[7]) << 16);
        *(uint4*)(tb2 + ((size_t)(b * 16 + cb) * 2048 + n) * 32 + cc) = o;
    }
    #pragma unroll
    for (int off = 32; off > 0; off >>= 1) {
        #pragma unroll
        for (int j = 0; j < 8; ++j) acc[j] += __shfl_xor(acc[j], off, 64);
    }
    if (lane == 0) {
        float lg[8];
        #pragma unroll
        for (int j = 0; j < 8; ++j)
            lg[j] = acc[j] + gate_b[j] + GENO_RATIO * geno_out[b * K_ + j];
        int i0 = 0; float v0m = lg[0];
        #pragma unroll
        for (int j = 1; j < 8; ++j) if (lg[j] > v0m) { v0m = lg[j]; i0 = j; }
        int i1 = -1; float v1m = -1e30f;
        #pragma unroll
        for (int j = 0; j < 8; ++j) if (j != i0 && lg[j] > v1m) { v1m = lg[j]; i1 = j; }
        float e = expf(v1m - v0m);
        float w0 = 1.f / (1.f + e);
        float w1 = e / (1.f + e);
        w0 = fmaxf(w0, EPS); w1 = fmaxf(w1, EPS);
        float s = w0 + w1; w0 /= s; w1 /= s;
        tpi[t] = i0 | (i1 << 4);
        tpw[t] = make_float2(w0, w1);
    }
}

// list build: one block per batch b; LDS counters only, zero global atomics.
__global__ __launch_bounds__(1024) void k_build(const int* __restrict__ tpi,
                                                const float2* __restrict__ tpw,
                                                int* __restrict__ cnt,
                                                float* __restrict__ mass,
                                                int* __restrict__ ln,
                                                float* __restrict__ lw) {
    int b = blockIdx.x;
    __shared__ int   lcnt[8];
    __shared__ float lmass[8];
    int tid = threadIdx.x;
    if (tid < 8) { lcnt[tid] = 0; lmass[tid] = 0.f; }
    __syncthreads();
    for (int n = tid; n < N_; n += 1024) {
        int pk = tpi[b * N_ + n];
        float2 w = tpw[b * N_ + n];
        int i0 = pk & 15, i1 = pk >> 4;
        int pos0 = atomicAdd(&lcnt[i0], 1);
        ln[(b * 8 + i0) * N_ + pos0] = n;
        lw[(b * 8 + i0) * N_ + pos0] = w.x;
        atomicAdd(&lmass[i0], w.x);
        int pos1 = atomicAdd(&lcnt[i1], 1);
        ln[(b * 8 + i1) * N_ + pos1] = n;
        lw[(b * 8 + i1) * N_ + pos1] = w.y;
        atomicAdd(&lmass[i1], w.y);
    }
    __syncthreads();
    if (tid < 8) {
        cnt[b * 8 + tid]  = lcnt[tid];
        mass[b * 8 + tid] = lmass[tid];
    }
}

// transpose + convert into K-chunk-tiled layout:
// w1t2[k][cb][n][cc] = bf16(w1[k][cb*32+cc][n])
__global__ __launch_bounds__(256) void k_w1t(const float* __restrict__ w1,
                                             ushort* __restrict__ w1t2) {
    int k = blockIdx.z; int c0 = blockIdx.x * 64; int n0 = blockIdx.y * 64;
    __shared__ float tile[64][65];
    int t = threadIdx.x;
    int tr = t >> 4;          // 0..15
    int tc4 = (t & 15) * 4;   // 0..60
    const float* src = w1 + (size_t)k * C_ * C_;
    #pragma unroll
    for (int i = 0; i < 4; ++i) {
        int c = c0 + tr + i * 16;
        float4 v = *(const float4*)(src + (size_t)c * C_ + n0 + tc4);
        tile[tr + i * 16][tc4 + 0] = v.x; tile[tr + i * 16][tc4 + 1] = v.y;
        tile[tr + i * 16][tc4 + 2] = v.z; tile[tr + i * 16][tc4 + 3] = v.w;
    }
    __syncthreads();
    #pragma unroll
    for (int i = 0; i < 4; ++i) {
        int rr = tr + i * 16;        // n - n0
        int n = n0 + rr;
        int c = c0 + tc4;            // 4 consecutive c, within one 32-chunk
        int cb = c >> 5, cc = c & 31;
        uint2 o;
        o.x = (unsigned)f2bf(tile[tc4 + 0][rr]) | ((unsigned)f2bf(tile[tc4 + 1][rr]) << 16);
        o.y = (unsigned)f2bf(tile[tc4 + 2][rr]) | ((unsigned)f2bf(tile[tc4 + 3][rr]) << 16);
        *(uint2*)(w1t2 + ((size_t)(k * 16 + cb) * 512 + n) * 32 + cc) = o;
    }
}

// grouped GEMM1, MFMA bf16. grid(p=64 fast, m=32 slow, h=2 channel-half).
// B: coalesced fragment loads from K-tiled w1t2, VGPR double-buffered.
// A: gathered rows staged once per block in padded LDS (dbuf).
__global__ __launch_bounds__(256) void k_ffn1(const ushort* __restrict__ tb2,
                                              const ushort* __restrict__ w1t2,
                                              const float* __restrict__ b1,
                                              const int* __restrict__ cnt,
                                              const int* __restrict__ ln,
                                              const float* __restrict__ lw,
                                              float* __restrict__ hsum) {
    int p = blockIdx.x; int b = p >> 3; int k = p & 7;
    int count = cnt[p];
    int m0 = blockIdx.y * 64;
    if (m0 >= count) return;
    int h = blockIdx.z;          // channel half: [h*256, h*256+256)

    __shared__ ushort As[2][64 * 36];   // 64 rows x 32 bf16, stride 36 ushorts
    __shared__ int   ns_s[64];
    __shared__ float wls_s[64];

    int tid = threadIdx.x;
    if (tid < 64) {
        int mi = m0 + tid;
        bool v = mi < count;
        ns_s[tid]  = v ? ln[p * N_ + mi] : 0;
        wls_s[tid] = v ? lw[p * N_ + mi] : 0.f;
    }
    __syncthreads();

    int wv = tid >> 6, lane = tid & 63;
    int ln15 = lane & 15, q = lane >> 4;

    // A staging: thread t handles row r=t>>2, 16B piece q4=t&3
    int r = tid >> 2, q4 = tid & 3;
    const ushort* agbase = tb2 + ((size_t)(b * 16) * 2048 + ns_s[r]) * 32 + q4 * 8;
    ushort* awr = &As[0][r * 36 + q4 * 8];

    // B: wave wv owns channels h*256 + wv*64 + j*16, j=0..3
    const ushort* bbase = w1t2 +
        ((size_t)(k * 16) * 512 + h * 256 + wv * 64 + ln15) * 32 + q * 8;

    f32x4 acc[4][4];
    #pragma unroll
    for (int mt = 0; mt < 4; ++mt)
        #pragma unroll
        for (int j = 0; j < 4; ++j) acc[mt][j] = (f32x4){0.f, 0.f, 0.f, 0.f};

    uint4 b_cur[4], b_nxt[4];
    {
        uint4 av = *(const uint4*)(agbase);
        *(uint4*)awr = av;
    }
    #pragma unroll
    for (int j = 0; j < 4; ++j) b_cur[j] = *(const uint4*)(bbase + j * 512);
    __syncthreads();

    const ushort* ards = &As[0][0];
    #pragma unroll
    for (int cb = 0; cb < 16; ++cb) {
        uint4 av;
        if (cb < 15) {
            av = *(const uint4*)(agbase + (size_t)(cb + 1) * 2048 * 32);
            #pragma unroll
            for (int j = 0; j < 4; ++j)
                b_nxt[j] = *(const uint4*)(bbase + (size_t)(cb + 1) * 16384 + j * 512);
        }
        bf16x8 afrag[4];
        const ushort* ab = ards + ((cb & 1) ? 64 * 36 : 0);
        #pragma unroll
        for (int mt = 0; mt < 4; ++mt)
            afrag[mt] = *(const bf16x8*)(ab + (mt * 16 + ln15) * 36 + q * 8);
        #pragma unroll
        for (int mt = 0; mt < 4; ++mt)
            #pragma unroll
            for (int j = 0; j < 4; ++j)
                acc[mt][j] = __builtin_amdgcn_mfma_f32_16x16x32_bf16(
                    afrag[mt], as_bf(b_cur[j]), acc[mt][j], 0, 0, 0);
        if (cb < 15) {
            *(uint4*)(awr + (((cb + 1) & 1) ? 64 * 36 : 0)) = av;
            #pragma unroll
            for (int j = 0; j < 4; ++j) b_cur[j] = b_nxt[j];
        }
        __syncthreads();
    }

    // epilogue: bias+relu+gate-weight; reduce 4 q-lanes; 1 atomic per column
    float wrow[4][4];
    #pragma unroll
    for (int mt = 0; mt < 4; ++mt)
        #pragma unroll
        for (int rr = 0; rr < 4; ++rr) wrow[mt][rr] = wls_s[mt * 16 + q * 4 + rr];
    const float* b1k = b1 + k * C_;
    float* hp = hsum + (size_t)p * C_;
    #pragma unroll
    for (int j = 0; j < 4; ++j) {
        int n = h * 256 + wv * 64 + j * 16 + ln15;
        float bias = b1k[n];
        float s = 0.f;
        #pragma unroll
        for (int mt = 0; mt < 4; ++mt)
            #pragma unroll
            for (int rr = 0; rr < 4; ++rr)
                s += wrow[mt][rr] * fmaxf(acc[mt][j][rr] + bias, 0.f);
        s += __shfl_xor(s, 16, 64);
        s += __shfl_xor(s, 32, 64);
        if (q == 0) atomicAdd(&hp[n], s);
    }
}

// combine partials: ctmp[b,k,e] += sum_{c in chunk} hsum[b,k,c] * w2[k,c,e]
__global__ __launch_bounds__(256) void k_comb(const float* __restrict__ hsum,
                                              const float* __restrict__ w2,
                                              float* __restrict__ ctmp) {
    int et = blockIdx.x, k = blockIdx.y, cc = blockIdx.z;
    int e0 = et * 64, c0 = cc * 128;
    __shared__ float hs[8][128];
    int t = threadIdx.x;
    for (int i = t; i < 1024; i += 256) {
        int b = i >> 7, c = i & 127;
        hs[b][c] = hsum[(size_t)((b * 8 + k) << 9) + c0 + c];
    }
    __syncthreads();
    int e = e0 + (t & 63); int g = t >> 6;
    float a0 = 0.f, a1 = 0.f;
    const float* w2p = w2 + (size_t)k * C_ * C_ + e;
    #pragma unroll 4
    for (int c = 0; c < 128; ++c) {
        float wv = w2p[(size_t)(c0 + c) * C_];
        a0 = fmaf(hs[g][c], wv, a0);
        a1 = fmaf(hs[g + 4][c], wv, a1);
    }
    atomicAdd(&ctmp[((g * 8 + k) << 9) + e], a0);
    atomicAdd(&ctmp[(((g + 4) * 8 + k) << 9) + e], a1);
}

// finalize: centers = (ctmp + b2*mass)/max(mass,eps); thread0 writes lb_loss
__global__ __launch_bounds__(256) void k_fin(const float* __restrict__ ctmp,
                                             const float* __restrict__ b2,
                                             const float* __restrict__ mass,
                                             const int* __restrict__ cnt,
                                             float* __restrict__ out) {
    int i = blockIdx.x * 256 + threadIdx.x;  // 0..32767
    int b = i >> 12; int ke = i & 4095; int k = ke >> 9;
    float m = mass[b * 8 + k];
    out[i] = (ctmp[i] + b2[ke] * m) / fmaxf(m, EPS);
    if (i == 0) {
        float u[8]; float s = 0.f;
        for (int kk = 0; kk < 8; ++kk) {
            int ck = 0;
            for (int bb = 0; bb < 8; ++bb) ck += cnt[bb * K_ + kk];
            u[kk] = (float)ck / (float)(B_ * N_);
            s += u[kk];
        }
        float mean = s / 8.f;
        float var = 0.f;
        for (int kk = 0; kk < 8; ++kk) { float d = u[kk] - mean; var += d * d; }
        var /= 8.f;
        float denom = mean + EPS;
        out[B_ * K_ * C_] = var / (denom * denom);
    }
}

extern "C" void kernel_launch(void* const* d_in, const int* in_sizes, int n_in,
                              void* d_out, int out_size, void* d_ws, size_t ws_size,
                              hipStream_t stream) {
    (void)in_sizes; (void)n_in; (void)out_size; (void)ws_size;
    const float* tokens   = (const float*)d_in[0];
    const float* geno_vec = (const float*)d_in[1];
    const float* gate_w   = (const float*)d_in[2];
    const float* gate_b   = (const float*)d_in[3];
    const float* geno_w   = (const float*)d_in[4];
    const float* geno_b   = (const float*)d_in[5];
    const float* w1       = (const float*)d_in[6];
    const float* b1       = (const float*)d_in[7];
    const float* w2       = (const float*)d_in[8];
    const float* b2       = (const float*)d_in[9];
    float* out = (float*)d_out;
    float* ws  = (float*)d_ws;

    float*  geno_out = ws;                       // 64
    int*    cnt      = (int*)(ws + 64);          // 64
    float*  mass     = ws + 128;                 // 64
    float*  hsum     = ws + 192;                 // 32768
    float*  ctmp     = ws + 32960;               // 32768
    float*  lw       = ws + 65728;               // 131072
    int*    ln       = (int*)(ws + 196800);      // 131072
    ushort* w1t2     = (ushort*)(ws + 327872);   // 2,097,152 bf16 (4 MB)
    ushort* tb2      = (ushort*)(ws + 1376448);  // 8,388,608 bf16 (16.8 MB)
    // tpi/tpw overlay hsum/ctmp; consumed by k_build BEFORE the memset below.
    int*    tpi      = (int*)(ws + 192);                 // 16384 ints
    float2* tpw      = (float2*)(ws + 192 + 16384);      // 16384 float2

    k_geno<<<dim3(B_ * K_), dim3(64), 0, stream>>>(geno_vec, geno_w, geno_b, geno_out);
    k_gate<<<dim3(B_ * N_ / 4), dim3(256), 0, stream>>>(tokens, gate_w, gate_b, geno_out,
                                                        tpi, tpw, tb2);
    k_build<<<dim3(B_), dim3(1024), 0, stream>>>(tpi, tpw, cnt, mass, ln, lw);
    // zero hsum + ctmp (after tpi/tpw consumed)
    hipMemsetAsync(ws + 192, 0, (size_t)(2 * B_ * K_ * C_) * sizeof(float), stream);
    k_w1t<<<dim3(8, 8, K_), dim3(256), 0, stream>>>(w1, w1t2);
    k_ffn1<<<dim3(B_ * K_, N_ / 64, 2), dim3(256), 0, stream>>>(tb2, w1t2, b1,
                                                                cnt, ln, lw, hsum);
    k_comb<<<dim3(8, K_, 4), dim3(256), 0, stream>>>(hsum, w2, ctmp);
    k_fin<<<dim3(128), dim3(256), 0, stream>>>(ctmp, b2, mass, cnt, out);
}

// Round 7
// 208.709 us; speedup vs baseline: 5.2177x; 1.0212x over previous
//
#include <hip/hip_runtime.h>
#include <math.h>

#define B_ 8
#define N_ 2048
#define C_ 512
#define K_ 8
#define EPS 1e-6f
#define GENO_RATIO 0.1f

typedef __bf16 bf16x8 __attribute__((ext_vector_type(8)));
typedef float f32x4 __attribute__((ext_vector_type(4)));

__device__ __forceinline__ ushort f2bf(float x) {
    unsigned int u = __float_as_uint(x);
    u += 0x7fffu + ((u >> 16) & 1u);   // RNE (inputs are finite)
    return (ushort)(u >> 16);
}

__device__ __forceinline__ bf16x8 as_bf(uint4 x) {
    union { uint4 u; bf16x8 b; } t; t.u = x; return t.b;
}

// ---------------------------------------------------------------------------
// ws layout (float element offsets):
// [0,64)               geno logits [B,K]
// [64,128)             cnt (int)   [B,K]
// [128,192)            mass        [B,K]
// [192,32960)          hsum        [B,K,C]   (tpi/tpw overlay before memset)
// [32960,65728)        ctmp        [B,K,C]
// [65728,196800)       lw          [B,K,N]
// [196800,327872)      ln (int)    [B,K,N]
// [327872,1376448)     w1t2 (bf16) [K][16 cb][512 n][32 cc]   4 MB  (K-tiled)
// [1376448,5570752)    tb2  (bf16) [B][16 cb][2048 n][32 cc]  16.8 MB
// ---------------------------------------------------------------------------

__global__ __launch_bounds__(64) void k_geno(const float* __restrict__ geno_vec,
                                             const float* __restrict__ geno_w,
                                             const float* __restrict__ geno_b,
                                             float* __restrict__ geno_out) {
    int p = blockIdx.x; int b = p >> 3; int k = p & 7;
    int lane = threadIdx.x;
    float acc = 0.f;
    #pragma unroll
    for (int i = 0; i < C_ / 64; ++i) {
        int c = lane + 64 * i;
        acc += geno_vec[b * C_ + c] * geno_w[c * K_ + k];
    }
    #pragma unroll
    for (int off = 32; off > 0; off >>= 1) acc += __shfl_xor(acc, off, 64);
    if (lane == 0) geno_out[p] = acc + geno_b[k];
}

// gating: one wave per token; lane owns 8 contiguous channels.
__global__ __launch_bounds__(256) void k_gate(const float* __restrict__ tokens,
                                              const float* __restrict__ gate_w,
                                              const float* __restrict__ gate_b,
                                              const float* __restrict__ geno_out,
                                              int* __restrict__ tpi,
                                              float2* __restrict__ tpw,
                                              ushort* __restrict__ tb2) {
    int wave = threadIdx.x >> 6;
    int lane = threadIdx.x & 63;
    int t = blockIdx.x * 4 + wave;
    int b = t >> 11;
    int n = t & 2047;
    const float* trow = tokens + (size_t)t * C_;
    int c0 = lane * 8;
    float4 v0 = *(const float4*)(trow + c0);
    float4 v1 = *(const float4*)(trow + c0 + 4);
    float tv[8] = {v0.x, v0.y, v0.z, v0.w, v1.x, v1.y, v1.z, v1.w};

    float acc[8] = {0.f,0.f,0.f,0.f,0.f,0.f,0.f,0.f};
    #pragma unroll
    for (int i = 0; i < 8; ++i) {
        const float4* g4 = (const float4*)(gate_w + (size_t)(c0 + i) * K_);
        float4 g0 = g4[0], g1 = g4[1];
        acc[0] = fmaf(tv[i], g0.x, acc[0]); acc[1] = fmaf(tv[i], g0.y, acc[1]);
        acc[2] = fmaf(tv[i], g0.z, acc[2]); acc[3] = fmaf(tv[i], g0.w, acc[3]);
        acc[4] = fmaf(tv[i], g1.x, acc[4]); acc[5] = fmaf(tv[i], g1.y, acc[5]);
        acc[6] = fmaf(tv[i], g1.z, acc[6]); acc[7] = fmaf(tv[i], g1.w, acc[7]);
    }
    {
        int cb = c0 >> 5, cc = c0 & 31;
        uint4 o;
        o.x = (unsigned)f2bf(tv[0]) | ((unsigned)f2bf(tv[1]) << 16);
        o.y = (unsigned)f2bf(tv[2]) | ((unsigned)f2bf(tv[3]) << 16);
        o.z = (unsigned)f2bf(tv[4]) | ((unsigned)f2bf(tv[5]) << 16);
        o.w = (unsigned)f2bf(tv[6]) | ((unsigned)f2bf(tv[7]) << 16);
        *(uint4*)(tb2 + ((size_t)(b * 16 + cb) * 2048 + n) * 32 + cc) = o;
    }
    #pragma unroll
    for (int off = 32; off > 0; off >>= 1) {
        #pragma unroll
        for (int j = 0; j < 8; ++j) acc[j] += __shfl_xor(acc[j], off, 64);
    }
    if (lane == 0) {
        float lg[8];
        #pragma unroll
        for (int j = 0; j < 8; ++j)
            lg[j] = acc[j] + gate_b[j] + GENO_RATIO * geno_out[b * K_ + j];
        int i0 = 0; float v0m = lg[0];
        #pragma unroll
        for (int j = 1; j < 8; ++j) if (lg[j] > v0m) { v0m = lg[j]; i0 = j; }
        int i1 = -1; float v1m = -1e30f;
        #pragma unroll
        for (int j = 0; j < 8; ++j) if (j != i0 && lg[j] > v1m) { v1m = lg[j]; i1 = j; }
        float e = expf(v1m - v0m);
        float w0 = 1.f / (1.f + e);
        float w1 = e / (1.f + e);
        w0 = fmaxf(w0, EPS); w1 = fmaxf(w1, EPS);
        float s = w0 + w1; w0 /= s; w1 /= s;
        tpi[t] = i0 | (i1 << 4);
        tpw[t] = make_float2(w0, w1);
    }
}

// list build v2: one block per batch; wave-aggregated LDS atomics
// (ballot + popcount prefix -> 2 atomics per wave per expert, not 128).
__global__ __launch_bounds__(1024) void k_build(const int* __restrict__ tpi,
                                                const float2* __restrict__ tpw,
                                                int* __restrict__ cnt,
                                                float* __restrict__ mass,
                                                int* __restrict__ ln,
                                                float* __restrict__ lw) {
    int b = blockIdx.x;
    __shared__ int   lcnt[8];
    __shared__ float lmass[8];
    int tid = threadIdx.x;
    if (tid < 8) { lcnt[tid] = 0; lmass[tid] = 0.f; }
    __syncthreads();
    int ww = tid >> 6, lane = tid & 63;
    unsigned long long lt = (1ull << lane) - 1ull;
    #pragma unroll
    for (int it = 0; it < 2; ++it) {
        int n = it * 1024 + ww * 64 + lane;
        int pk = tpi[b * N_ + n];
        float2 w = tpw[b * N_ + n];
        int i0 = pk & 15, i1 = pk >> 4;
        #pragma unroll
        for (int kk = 0; kk < 8; ++kk) {
            unsigned long long m0 = __ballot(i0 == kk);
            unsigned long long m1 = __ballot(i1 == kk);
            int c0 = __popcll(m0), c1 = __popcll(m1);
            int base = 0;
            if (lane == 0 && (c0 + c1) > 0) base = atomicAdd(&lcnt[kk], c0 + c1);
            base = __shfl(base, 0, 64);
            int pbase = (b * 8 + kk) * N_;
            if (i0 == kk) {
                int pos = base + __popcll(m0 & lt);
                ln[pbase + pos] = n; lw[pbase + pos] = w.x;
            }
            if (i1 == kk) {
                int pos = base + c0 + __popcll(m1 & lt);
                ln[pbase + pos] = n; lw[pbase + pos] = w.y;
            }
            float s = (i0 == kk ? w.x : 0.f) + (i1 == kk ? w.y : 0.f);
            #pragma unroll
            for (int off = 32; off > 0; off >>= 1) s += __shfl_xor(s, off, 64);
            if (lane == 0 && s != 0.f) atomicAdd(&lmass[kk], s);
        }
    }
    __syncthreads();
    if (tid < 8) {
        cnt[b * 8 + tid]  = lcnt[tid];
        mass[b * 8 + tid] = lmass[tid];
    }
}

// transpose + convert into K-chunk-tiled layout:
// w1t2[k][cb][n][cc] = bf16(w1[k][cb*32+cc][n])
__global__ __launch_bounds__(256) void k_w1t(const float* __restrict__ w1,
                                             ushort* __restrict__ w1t2) {
    int k = blockIdx.z; int c0 = blockIdx.x * 64; int n0 = blockIdx.y * 64;
    __shared__ float tile[64][65];
    int t = threadIdx.x;
    int tr = t >> 4;          // 0..15
    int tc4 = (t & 15) * 4;   // 0..60
    const float* src = w1 + (size_t)k * C_ * C_;
    #pragma unroll
    for (int i = 0; i < 4; ++i) {
        int c = c0 + tr + i * 16;
        float4 v = *(const float4*)(src + (size_t)c * C_ + n0 + tc4);
        tile[tr + i * 16][tc4 + 0] = v.x; tile[tr + i * 16][tc4 + 1] = v.y;
        tile[tr + i * 16][tc4 + 2] = v.z; tile[tr + i * 16][tc4 + 3] = v.w;
    }
    __syncthreads();
    #pragma unroll
    for (int i = 0; i < 4; ++i) {
        int rr = tr + i * 16;        // n - n0
        int n = n0 + rr;
        int c = c0 + tc4;
        int cb = c >> 5, cc = c & 31;
        uint2 o;
        o.x = (unsigned)f2bf(tile[tc4 + 0][rr]) | ((unsigned)f2bf(tile[tc4 + 1][rr]) << 16);
        o.y = (unsigned)f2bf(tile[tc4 + 2][rr]) | ((unsigned)f2bf(tile[tc4 + 3][rr]) << 16);
        *(uint2*)(w1t2 + ((size_t)(k * 16 + cb) * 512 + n) * 32 + cc) = o;
    }
}

// grouped GEMM1, MFMA bf16, fully barrier-free K-loop: per-lane direct
// fragment loads (A gathered 16x64B; B contiguous 1KB from K-tiled w1t2),
// VGPR double-buffered. grid(p fast, m, h).
__global__ __launch_bounds__(256) void k_ffn1(const ushort* __restrict__ tb2,
                                              const ushort* __restrict__ w1t2,
                                              const float* __restrict__ b1,
                                              const int* __restrict__ cnt,
                                              const int* __restrict__ ln,
                                              const float* __restrict__ lw,
                                              float* __restrict__ hsum) {
    int p = blockIdx.x; int b = p >> 3; int k = p & 7;
    int count = cnt[p];
    int m0 = blockIdx.y * 64;
    if (m0 >= count) return;
    int h = blockIdx.z;          // channel half: [h*256, h*256+256)

    __shared__ int   ns_s[64];
    __shared__ float wls_s[64];
    int tid = threadIdx.x;
    if (tid < 64) {
        int mi = m0 + tid;
        bool v = mi < count;
        ns_s[tid]  = v ? ln[p * N_ + mi] : 0;
        wls_s[tid] = v ? lw[p * N_ + mi] : 0.f;
    }
    __syncthreads();

    int wv = tid >> 6, lane = tid & 63;
    int ln15 = lane & 15, q = lane >> 4;

    // A: lane's fragment rows for mt=0..3 (chunk stride 2048*32 ushorts)
    const ushort* ap[4];
    #pragma unroll
    for (int mt = 0; mt < 4; ++mt)
        ap[mt] = tb2 + ((size_t)(b * 16) * 2048 + ns_s[mt * 16 + ln15]) * 32 + q * 8;
    // B: wave wv owns channels h*256 + wv*64 + j*16 (chunk stride 512*32)
    const ushort* bbase = w1t2 +
        ((size_t)(k * 16) * 512 + h * 256 + wv * 64 + ln15) * 32 + q * 8;

    f32x4 acc[4][4];
    #pragma unroll
    for (int mt = 0; mt < 4; ++mt)
        #pragma unroll
        for (int j = 0; j < 4; ++j) acc[mt][j] = (f32x4){0.f, 0.f, 0.f, 0.f};

    uint4 a_cur[4], b_cur[4], a_nxt[4], b_nxt[4];
    #pragma unroll
    for (int mt = 0; mt < 4; ++mt) a_cur[mt] = *(const uint4*)(ap[mt]);
    #pragma unroll
    for (int j = 0; j < 4; ++j)  b_cur[j] = *(const uint4*)(bbase + j * 512);

    #pragma unroll
    for (int cb = 0; cb < 16; ++cb) {
        if (cb < 15) {
            #pragma unroll
            for (int mt = 0; mt < 4; ++mt)
                a_nxt[mt] = *(const uint4*)(ap[mt] + (size_t)(cb + 1) * 65536);
            #pragma unroll
            for (int j = 0; j < 4; ++j)
                b_nxt[j] = *(const uint4*)(bbase + (size_t)(cb + 1) * 16384 + j * 512);
        }
        #pragma unroll
        for (int mt = 0; mt < 4; ++mt)
            #pragma unroll
            for (int j = 0; j < 4; ++j)
                acc[mt][j] = __builtin_amdgcn_mfma_f32_16x16x32_bf16(
                    as_bf(a_cur[mt]), as_bf(b_cur[j]), acc[mt][j], 0, 0, 0);
        #pragma unroll
        for (int mt = 0; mt < 4; ++mt) a_cur[mt] = a_nxt[mt];
        #pragma unroll
        for (int j = 0; j < 4; ++j)  b_cur[j] = b_nxt[j];
    }

    // epilogue: bias+relu+gate-weight; reduce 4 q-lanes; 1 atomic per column
    float wrow[4][4];
    #pragma unroll
    for (int mt = 0; mt < 4; ++mt)
        #pragma unroll
        for (int rr = 0; rr < 4; ++rr) wrow[mt][rr] = wls_s[mt * 16 + q * 4 + rr];
    const float* b1k = b1 + k * C_;
    float* hp = hsum + (size_t)p * C_;
    #pragma unroll
    for (int j = 0; j < 4; ++j) {
        int n = h * 256 + wv * 64 + j * 16 + ln15;
        float bias = b1k[n];
        float s = 0.f;
        #pragma unroll
        for (int mt = 0; mt < 4; ++mt)
            #pragma unroll
            for (int rr = 0; rr < 4; ++rr)
                s += wrow[mt][rr] * fmaxf(acc[mt][j][rr] + bias, 0.f);
        s += __shfl_xor(s, 16, 64);
        s += __shfl_xor(s, 32, 64);
        if (q == 0) atomicAdd(&hp[n], s);
    }
}

// combine partials: ctmp[b,k,e] += sum_{c in 64-chunk} hsum[b,k,c]*w2[k,c,e]
__global__ __launch_bounds__(256) void k_comb(const float* __restrict__ hsum,
                                              const float* __restrict__ w2,
                                              float* __restrict__ ctmp) {
    int et = blockIdx.x, k = blockIdx.y, cc = blockIdx.z;
    int e0 = et * 64, c0 = cc * 64;
    __shared__ float hs[8][64];
    int t = threadIdx.x;
    for (int i = t; i < 512; i += 256) {
        int b = i >> 6, c = i & 63;
        hs[b][c] = hsum[(size_t)((b * 8 + k) << 9) + c0 + c];
    }
    __syncthreads();
    int e = e0 + (t & 63); int g = t >> 6;
    float a0 = 0.f, a1 = 0.f;
    const float* w2p = w2 + (size_t)k * C_ * C_ + e;
    #pragma unroll 4
    for (int c = 0; c < 64; ++c) {
        float wv = w2p[(size_t)(c0 + c) * C_];
        a0 = fmaf(hs[g][c], wv, a0);
        a1 = fmaf(hs[g + 4][c], wv, a1);
    }
    atomicAdd(&ctmp[((g * 8 + k) << 9) + e], a0);
    atomicAdd(&ctmp[(((g + 4) * 8 + k) << 9) + e], a1);
}

// finalize: centers = (ctmp + b2*mass)/max(mass,eps); thread0 writes lb_loss
__global__ __launch_bounds__(256) void k_fin(const float* __restrict__ ctmp,
                                             const float* __restrict__ b2,
                                             const float* __restrict__ mass,
                                             const int* __restrict__ cnt,
                                             float* __restrict__ out) {
    int i = blockIdx.x * 256 + threadIdx.x;  // 0..32767
    int b = i >> 12; int ke = i & 4095; int k = ke >> 9;
    float m = mass[b * 8 + k];
    out[i] = (ctmp[i] + b2[ke] * m) / fmaxf(m, EPS);
    if (i == 0) {
        float u[8]; float s = 0.f;
        for (int kk = 0; kk < 8; ++kk) {
            int ck = 0;
            for (int bb = 0; bb < 8; ++bb) ck += cnt[bb * K_ + kk];
            u[kk] = (float)ck / (float)(B_ * N_);
            s += u[kk];
        }
        float mean = s / 8.f;
        float var = 0.f;
        for (int kk = 0; kk < 8; ++kk) { float d = u[kk] - mean; var += d * d; }
        var /= 8.f;
        float denom = mean + EPS;
        out[B_ * K_ * C_] = var / (denom * denom);
    }
}

extern "C" void kernel_launch(void* const* d_in, const int* in_sizes, int n_in,
                              void* d_out, int out_size, void* d_ws, size_t ws_size,
                              hipStream_t stream) {
    (void)in_sizes; (void)n_in; (void)out_size; (void)ws_size;
    const float* tokens   = (const float*)d_in[0];
    const float* geno_vec = (const float*)d_in[1];
    const float* gate_w   = (const float*)d_in[2];
    const float* gate_b   = (const float*)d_in[3];
    const float* geno_w   = (const float*)d_in[4];
    const float* geno_b   = (const float*)d_in[5];
    const float* w1       = (const float*)d_in[6];
    const float* b1       = (const float*)d_in[7];
    const float* w2       = (const float*)d_in[8];
    const float* b2       = (const float*)d_in[9];
    float* out = (float*)d_out;
    float* ws  = (float*)d_ws;

    float*  geno_out = ws;                       // 64
    int*    cnt      = (int*)(ws + 64);          // 64
    float*  mass     = ws + 128;                 // 64
    float*  hsum     = ws + 192;                 // 32768
    float*  ctmp     = ws + 32960;               // 32768
    float*  lw       = ws + 65728;               // 131072
    int*    ln       = (int*)(ws + 196800);      // 131072
    ushort* w1t2     = (ushort*)(ws + 327872);   // 2,097,152 bf16 (4 MB)
    ushort* tb2      = (ushort*)(ws + 1376448);  // 8,388,608 bf16 (16.8 MB)
    // tpi/tpw overlay hsum/ctmp; consumed by k_build BEFORE the memset below.
    int*    tpi      = (int*)(ws + 192);                 // 16384 ints
    float2* tpw      = (float2*)(ws + 192 + 16384);      // 16384 float2

    k_geno<<<dim3(B_ * K_), dim3(64), 0, stream>>>(geno_vec, geno_w, geno_b, geno_out);
    k_gate<<<dim3(B_ * N_ / 4), dim3(256), 0, stream>>>(tokens, gate_w, gate_b, geno_out,
                                                        tpi, tpw, tb2);
    k_build<<<dim3(B_), dim3(1024), 0, stream>>>(tpi, tpw, cnt, mass, ln, lw);
    // zero hsum + ctmp (after tpi/tpw consumed)
    hipMemsetAsync(ws + 192, 0, (size_t)(2 * B_ * K_ * C_) * sizeof(float), stream);
    k_w1t<<<dim3(8, 8, K_), dim3(256), 0, stream>>>(w1, w1t2);
    k_ffn1<<<dim3(B_ * K_, N_ / 64, 2), dim3(256), 0, stream>>>(tb2, w1t2, b1,
                                                                cnt, ln, lw, hsum);
    k_comb<<<dim3(8, K_, 8), dim3(256), 0, stream>>>(hsum, w2, ctmp);
    k_fin<<<dim3(128), dim3(256), 0, stream>>>(ctmp, b2, mass, cnt, out);
}

// Round 8
// 189.611 us; speedup vs baseline: 5.7433x; 1.1007x over previous
//
#include <hip/hip_runtime.h>
#include <math.h>

#define B_ 8
#define N_ 2048
#define C_ 512
#define K_ 8
#define EPS 1e-6f
#define GENO_RATIO 0.1f

typedef __bf16 bf16x8 __attribute__((ext_vector_type(8)));
typedef float f32x4 __attribute__((ext_vector_type(4)));

__device__ __forceinline__ ushort f2bf(float x) {
    unsigned int u = __float_as_uint(x);
    u += 0x7fffu + ((u >> 16) & 1u);   // RNE (inputs are finite)
    return (ushort)(u >> 16);
}

__device__ __forceinline__ bf16x8 as_bf(uint4 x) {
    union { uint4 u; bf16x8 b; } t; t.u = x; return t.b;
}

// ---------------------------------------------------------------------------
// ws layout (float element offsets):
// [64,128)             cnt (int)   [B,K]
// [128,192)            mass        [B,K]
// [192,32960)          hsum        [B,K,C]    (tpi overlays hsum[0:16384))
// [32960,65728)        ctmp        [B,K,C]    (tpw overlays all of ctmp)
// [65728,196800)       lw          [B,K,N]
// [196800,327872)      ln (int)    [B,K,N]
// [327872,1376448)     w1t2 (bf16) [K][16 cb][512 n][32 cc]   4 MB  (K-tiled)
// [1376448,5570752)    tb2  (bf16) [B][16 cb][2048 n][32 cc]  16.8 MB
// tpi/tpw overlay is resolved inside k_build: each block reads ONLY its own
// b-slice of tpi/tpw into registers, __syncthreads(), then zeroes exactly the
// regions it read (plus its share of untouched hsum) -> no cross-block race.
// ---------------------------------------------------------------------------

// gating + geno fused: one wave per token; gate_w/geno_w staged transposed in
// LDS (coalesced ds_read_b128 instead of 32B gathers). No atomics.
__global__ __launch_bounds__(256) void k_gate(const float* __restrict__ tokens,
                                              const float* __restrict__ gate_w,
                                              const float* __restrict__ gate_b,
                                              const float* __restrict__ geno_vec,
                                              const float* __restrict__ geno_w,
                                              const float* __restrict__ geno_b,
                                              int* __restrict__ tpi,
                                              float2* __restrict__ tpw,
                                              ushort* __restrict__ tb2) {
    __shared__ float gwT[8][512];   // gate_w transposed [k][c]
    __shared__ float qwT[8][512];   // geno_w transposed [k][c]
    int tid = threadIdx.x;
    for (int i = tid; i < 1024; i += 256) {
        int c = i >> 1, j0 = (i & 1) * 4;
        float4 v = *(const float4*)(gate_w + i * 4);
        gwT[j0 + 0][c] = v.x; gwT[j0 + 1][c] = v.y;
        gwT[j0 + 2][c] = v.z; gwT[j0 + 3][c] = v.w;
        float4 u = *(const float4*)(geno_w + i * 4);
        qwT[j0 + 0][c] = u.x; qwT[j0 + 1][c] = u.y;
        qwT[j0 + 2][c] = u.z; qwT[j0 + 3][c] = u.w;
    }
    __syncthreads();

    int wave = tid >> 6, lane = tid & 63;
    int t = blockIdx.x * 4 + wave;
    int b = t >> 11;
    int n = t & 2047;
    int c0 = lane * 8;
    const float* trow = tokens + (size_t)t * C_;
    float4 v0 = *(const float4*)(trow + c0);
    float4 v1 = *(const float4*)(trow + c0 + 4);
    const float* grow = geno_vec + (size_t)b * C_;
    float4 gy0 = *(const float4*)(grow + c0);
    float4 gy1 = *(const float4*)(grow + c0 + 4);
    float tv[8] = {v0.x, v0.y, v0.z, v0.w, v1.x, v1.y, v1.z, v1.w};
    float gv[8] = {gy0.x, gy0.y, gy0.z, gy0.w, gy1.x, gy1.y, gy1.z, gy1.w};

    float acc[8];
    #pragma unroll
    for (int j = 0; j < 8; ++j) {
        float4 w0 = *(const float4*)&gwT[j][c0];
        float4 w1 = *(const float4*)&gwT[j][c0 + 4];
        float4 q0 = *(const float4*)&qwT[j][c0];
        float4 q1 = *(const float4*)&qwT[j][c0 + 4];
        float a = 0.f, g = 0.f;
        a = fmaf(tv[0], w0.x, a); a = fmaf(tv[1], w0.y, a);
        a = fmaf(tv[2], w0.z, a); a = fmaf(tv[3], w0.w, a);
        a = fmaf(tv[4], w1.x, a); a = fmaf(tv[5], w1.y, a);
        a = fmaf(tv[6], w1.z, a); a = fmaf(tv[7], w1.w, a);
        g = fmaf(gv[0], q0.x, g); g = fmaf(gv[1], q0.y, g);
        g = fmaf(gv[2], q0.z, g); g = fmaf(gv[3], q0.w, g);
        g = fmaf(gv[4], q1.x, g); g = fmaf(gv[5], q1.y, g);
        g = fmaf(gv[6], q1.z, g); g = fmaf(gv[7], q1.w, g);
        acc[j] = fmaf(GENO_RATIO, g, a);
    }
    // bf16 pack + K-tiled store (8 channels of one 32-chunk -> 16B contiguous)
    {
        int cb = c0 >> 5, cc = c0 & 31;
        uint4 o;
        o.x = (unsigned)f2bf(tv[0]) | ((unsigned)f2bf(tv[1]) << 16);
        o.y = (unsigned)f2bf(tv[2]) | ((unsigned)f2bf(tv[3]) << 16);
        o.z = (unsigned)f2bf(tv[4]) | ((unsigned)f2bf(tv[5]) << 16);
        o.w = (unsigned)f2bf(tv[6]) | ((unsigned)f2bf(tv[7]) << 16);
        *(uint4*)(tb2 + ((size_t)(b * 16 + cb) * 2048 + n) * 32 + cc) = o;
    }
    #pragma unroll
    for (int off = 32; off > 0; off >>= 1) {
        #pragma unroll
        for (int j = 0; j < 8; ++j) acc[j] += __shfl_xor(acc[j], off, 64);
    }
    if (lane == 0) {
        float lg[8];
        #pragma unroll
        for (int j = 0; j < 8; ++j)
            lg[j] = acc[j] + gate_b[j] + GENO_RATIO * geno_b[j];
        int i0 = 0; float v0m = lg[0];
        #pragma unroll
        for (int j = 1; j < 8; ++j) if (lg[j] > v0m) { v0m = lg[j]; i0 = j; }
        int i1 = -1; float v1m = -1e30f;
        #pragma unroll
        for (int j = 0; j < 8; ++j) if (j != i0 && lg[j] > v1m) { v1m = lg[j]; i1 = j; }
        float e = expf(v1m - v0m);
        float w0 = 1.f / (1.f + e);
        float w1 = e / (1.f + e);
        w0 = fmaxf(w0, EPS); w1 = fmaxf(w1, EPS);
        float s = w0 + w1; w0 /= s; w1 /= s;
        tpi[t] = i0 | (i1 << 4);
        tpw[t] = make_float2(w0, w1);
    }
}

// list build + zero hsum/ctmp. One block per batch b. Reads its own tpi/tpw
// slice into registers, barrier, zeroes the overlaid regions, then builds
// lists with wave-aggregated (ballot) LDS atomics.
__global__ __launch_bounds__(1024) void k_build(const int* __restrict__ tpi,
                                                const float2* __restrict__ tpw,
                                                int* __restrict__ cnt,
                                                float* __restrict__ mass,
                                                int* __restrict__ ln,
                                                float* __restrict__ lw,
                                                float* __restrict__ hsum,
                                                float* __restrict__ ctmp) {
    int b = blockIdx.x;
    __shared__ int   lcnt[8];
    __shared__ float lmass[8];
    int tid = threadIdx.x;
    if (tid < 8) { lcnt[tid] = 0; lmass[tid] = 0.f; }

    // read phase (this block's slice only)
    int pk[2]; float2 w[2];
    #pragma unroll
    for (int it = 0; it < 2; ++it) {
        int n = it * 1024 + tid;
        pk[it] = tpi[b * N_ + n];
        w[it]  = tpw[b * N_ + n];
    }
    __syncthreads();   // all reads of this block's tpi/tpw slice done

    // zero phase: exactly the regions this block read + its share of the rest
    {
        float4 z = {0.f, 0.f, 0.f, 0.f};
        float4* h4 = (float4*)hsum;   // 8192 float4 total
        if (tid < 512) h4[b * 512 + tid] = z;              // own tpi slice
        else           h4[4096 + b * 512 + (tid - 512)] = z; // upper half share
        float4* c4 = (float4*)ctmp;   // 8192 float4 total
        c4[b * 1024 + tid] = z;                            // own tpw slice
    }

    // ballot list build
    int lane = tid & 63;
    unsigned long long lt = (1ull << lane) - 1ull;
    #pragma unroll
    for (int it = 0; it < 2; ++it) {
        int n = it * 1024 + tid;
        int i0 = pk[it] & 15, i1 = pk[it] >> 4;
        #pragma unroll
        for (int kk = 0; kk < 8; ++kk) {
            unsigned long long m0 = __ballot(i0 == kk);
            unsigned long long m1 = __ballot(i1 == kk);
            int c0 = __popcll(m0), c1 = __popcll(m1);
            int base = 0;
            if (lane == 0 && (c0 + c1) > 0) base = atomicAdd(&lcnt[kk], c0 + c1);
            base = __shfl(base, 0, 64);
            int pbase = (b * 8 + kk) * N_;
            if (i0 == kk) {
                int pos = base + __popcll(m0 & lt);
                ln[pbase + pos] = n; lw[pbase + pos] = w[it].x;
            }
            if (i1 == kk) {
                int pos = base + c0 + __popcll(m1 & lt);
                ln[pbase + pos] = n; lw[pbase + pos] = w[it].y;
            }
            float s = (i0 == kk ? w[it].x : 0.f) + (i1 == kk ? w[it].y : 0.f);
            #pragma unroll
            for (int off = 32; off > 0; off >>= 1) s += __shfl_xor(s, off, 64);
            if (lane == 0 && s != 0.f) atomicAdd(&lmass[kk], s);
        }
    }
    __syncthreads();
    if (tid < 8) {
        cnt[b * 8 + tid]  = lcnt[tid];
        mass[b * 8 + tid] = lmass[tid];
    }
}

// transpose + convert into K-chunk-tiled layout:
// w1t2[k][cb][n][cc] = bf16(w1[k][cb*32+cc][n])
__global__ __launch_bounds__(256) void k_w1t(const float* __restrict__ w1,
                                             ushort* __restrict__ w1t2) {
    int k = blockIdx.z; int c0 = blockIdx.x * 64; int n0 = blockIdx.y * 64;
    __shared__ float tile[64][65];
    int t = threadIdx.x;
    int tr = t >> 4;          // 0..15
    int tc4 = (t & 15) * 4;   // 0..60
    const float* src = w1 + (size_t)k * C_ * C_;
    #pragma unroll
    for (int i = 0; i < 4; ++i) {
        int c = c0 + tr + i * 16;
        float4 v = *(const float4*)(src + (size_t)c * C_ + n0 + tc4);
        tile[tr + i * 16][tc4 + 0] = v.x; tile[tr + i * 16][tc4 + 1] = v.y;
        tile[tr + i * 16][tc4 + 2] = v.z; tile[tr + i * 16][tc4 + 3] = v.w;
    }
    __syncthreads();
    #pragma unroll
    for (int i = 0; i < 4; ++i) {
        int rr = tr + i * 16;        // n - n0
        int n = n0 + rr;
        int c = c0 + tc4;
        int cb = c >> 5, cc = c & 31;
        uint2 o;
        o.x = (unsigned)f2bf(tile[tc4 + 0][rr]) | ((unsigned)f2bf(tile[tc4 + 1][rr]) << 16);
        o.y = (unsigned)f2bf(tile[tc4 + 2][rr]) | ((unsigned)f2bf(tile[tc4 + 3][rr]) << 16);
        *(uint2*)(w1t2 + ((size_t)(k * 16 + cb) * 512 + n) * 32 + cc) = o;
    }
}

// grouped GEMM1, MFMA bf16, barrier-free K-loop, per-lane direct fragment
// loads, VGPR double-buffered. __launch_bounds__(256,2): 256-VGPR budget so
// the prefetch registers survive (R7's default bound collapsed the pipeline).
__global__ __launch_bounds__(256, 2) void k_ffn1(const ushort* __restrict__ tb2,
                                                 const ushort* __restrict__ w1t2,
                                                 const float* __restrict__ b1,
                                                 const int* __restrict__ cnt,
                                                 const int* __restrict__ ln,
                                                 const float* __restrict__ lw,
                                                 float* __restrict__ hsum) {
    int p = blockIdx.x; int b = p >> 3; int k = p & 7;
    int count = cnt[p];
    int m0 = blockIdx.y * 64;
    if (m0 >= count) return;
    int h = blockIdx.z;          // channel half: [h*256, h*256+256)

    __shared__ int   ns_s[64];
    __shared__ float wls_s[64];
    int tid = threadIdx.x;
    if (tid < 64) {
        int mi = m0 + tid;
        bool v = mi < count;
        ns_s[tid]  = v ? ln[p * N_ + mi] : 0;
        wls_s[tid] = v ? lw[p * N_ + mi] : 0.f;
    }
    __syncthreads();

    int wv = tid >> 6, lane = tid & 63;
    int ln15 = lane & 15, q = lane >> 4;

    const ushort* ap[4];
    #pragma unroll
    for (int mt = 0; mt < 4; ++mt)
        ap[mt] = tb2 + ((size_t)(b * 16) * 2048 + ns_s[mt * 16 + ln15]) * 32 + q * 8;
    const ushort* bbase = w1t2 +
        ((size_t)(k * 16) * 512 + h * 256 + wv * 64 + ln15) * 32 + q * 8;

    f32x4 acc[4][4];
    #pragma unroll
    for (int mt = 0; mt < 4; ++mt)
        #pragma unroll
        for (int j = 0; j < 4; ++j) acc[mt][j] = (f32x4){0.f, 0.f, 0.f, 0.f};

    uint4 a_cur[4], b_cur[4], a_nxt[4], b_nxt[4];
    #pragma unroll
    for (int mt = 0; mt < 4; ++mt) a_cur[mt] = *(const uint4*)(ap[mt]);
    #pragma unroll
    for (int j = 0; j < 4; ++j)  b_cur[j] = *(const uint4*)(bbase + j * 512);

    #pragma unroll
    for (int cb = 0; cb < 16; ++cb) {
        if (cb < 15) {
            #pragma unroll
            for (int mt = 0; mt < 4; ++mt)
                a_nxt[mt] = *(const uint4*)(ap[mt] + (size_t)(cb + 1) * 65536);
            #pragma unroll
            for (int j = 0; j < 4; ++j)
                b_nxt[j] = *(const uint4*)(bbase + (size_t)(cb + 1) * 16384 + j * 512);
        }
        #pragma unroll
        for (int mt = 0; mt < 4; ++mt)
            #pragma unroll
            for (int j = 0; j < 4; ++j)
                acc[mt][j] = __builtin_amdgcn_mfma_f32_16x16x32_bf16(
                    as_bf(a_cur[mt]), as_bf(b_cur[j]), acc[mt][j], 0, 0, 0);
        #pragma unroll
        for (int mt = 0; mt < 4; ++mt) a_cur[mt] = a_nxt[mt];
        #pragma unroll
        for (int j = 0; j < 4; ++j)  b_cur[j] = b_nxt[j];
    }

    // epilogue: bias+relu+gate-weight; reduce 4 q-lanes; 1 atomic per column
    float wrow[4][4];
    #pragma unroll
    for (int mt = 0; mt < 4; ++mt)
        #pragma unroll
        for (int rr = 0; rr < 4; ++rr) wrow[mt][rr] = wls_s[mt * 16 + q * 4 + rr];
    const float* b1k = b1 + k * C_;
    float* hp = hsum + (size_t)p * C_;
    #pragma unroll
    for (int j = 0; j < 4; ++j) {
        int n = h * 256 + wv * 64 + j * 16 + ln15;
        float bias = b1k[n];
        float s = 0.f;
        #pragma unroll
        for (int mt = 0; mt < 4; ++mt)
            #pragma unroll
            for (int rr = 0; rr < 4; ++rr)
                s += wrow[mt][rr] * fmaxf(acc[mt][j][rr] + bias, 0.f);
        s += __shfl_xor(s, 16, 64);
        s += __shfl_xor(s, 32, 64);
        if (q == 0) atomicAdd(&hp[n], s);
    }
}

// combine partials: ctmp[b,k,e] += sum_{c in 64-chunk} hsum[b,k,c]*w2[k,c,e]
__global__ __launch_bounds__(256) void k_comb(const float* __restrict__ hsum,
                                              const float* __restrict__ w2,
                                              float* __restrict__ ctmp) {
    int et = blockIdx.x, k = blockIdx.y, cc = blockIdx.z;
    int e0 = et * 64, c0 = cc * 64;
    __shared__ float hs[8][64];
    int t = threadIdx.x;
    for (int i = t; i < 512; i += 256) {
        int b = i >> 6, c = i & 63;
        hs[b][c] = hsum[(size_t)((b * 8 + k) << 9) + c0 + c];
    }
    __syncthreads();
    int e = e0 + (t & 63); int g = t >> 6;
    float a0 = 0.f, a1 = 0.f;
    const float* w2p = w2 + (size_t)k * C_ * C_ + e;
    #pragma unroll 4
    for (int c = 0; c < 64; ++c) {
        float wv = w2p[(size_t)(c0 + c) * C_];
        a0 = fmaf(hs[g][c], wv, a0);
        a1 = fmaf(hs[g + 4][c], wv, a1);
    }
    atomicAdd(&ctmp[((g * 8 + k) << 9) + e], a0);
    atomicAdd(&ctmp[(((g + 4) * 8 + k) << 9) + e], a1);
}

// finalize: centers = (ctmp + b2*mass)/max(mass,eps); thread0 writes lb_loss
__global__ __launch_bounds__(256) void k_fin(const float* __restrict__ ctmp,
                                             const float* __restrict__ b2,
                                             const float* __restrict__ mass,
                                             const int* __restrict__ cnt,
                                             float* __restrict__ out) {
    int i = blockIdx.x * 256 + threadIdx.x;  // 0..32767
    int b = i >> 12; int ke = i & 4095; int k = ke >> 9;
    float m = mass[b * 8 + k];
    out[i] = (ctmp[i] + b2[ke] * m) / fmaxf(m, EPS);
    if (i == 0) {
        float u[8]; float s = 0.f;
        for (int kk = 0; kk < 8; ++kk) {
            int ck = 0;
            for (int bb = 0; bb < 8; ++bb) ck += cnt[bb * K_ + kk];
            u[kk] = (float)ck / (float)(B_ * N_);
            s += u[kk];
        }
        float mean = s / 8.f;
        float var = 0.f;
        for (int kk = 0; kk < 8; ++kk) { float d = u[kk] - mean; var += d * d; }
        var /= 8.f;
        float denom = mean + EPS;
        out[B_ * K_ * C_] = var / (denom * denom);
    }
}

extern "C" void kernel_launch(void* const* d_in, const int* in_sizes, int n_in,
                              void* d_out, int out_size, void* d_ws, size_t ws_size,
                              hipStream_t stream) {
    (void)in_sizes; (void)n_in; (void)out_size; (void)ws_size;
    const float* tokens   = (const float*)d_in[0];
    const float* geno_vec = (const float*)d_in[1];
    const float* gate_w   = (const float*)d_in[2];
    const float* gate_b   = (const float*)d_in[3];
    const float* geno_w   = (const float*)d_in[4];
    const float* geno_b   = (const float*)d_in[5];
    const float* w1       = (const float*)d_in[6];
    const float* b1       = (const float*)d_in[7];
    const float* w2       = (const float*)d_in[8];
    const float* b2       = (const float*)d_in[9];
    float* out = (float*)d_out;
    float* ws  = (float*)d_ws;

    int*    cnt      = (int*)(ws + 64);          // 64
    float*  mass     = ws + 128;                 // 64
    float*  hsum     = ws + 192;                 // 32768
    float*  ctmp     = ws + 32960;               // 32768
    float*  lw       = ws + 65728;               // 131072
    int*    ln       = (int*)(ws + 196800);      // 131072
    ushort* w1t2     = (ushort*)(ws + 327872);   // 2,097,152 bf16 (4 MB)
    ushort* tb2      = (ushort*)(ws + 1376448);  // 8,388,608 bf16 (16.8 MB)
    // tpi overlays hsum[0:16384); tpw overlays ctmp. k_build consumes its own
    // slice, syncs, then zeroes exactly those regions (no cross-block race).
    int*    tpi      = (int*)hsum;               // 16384 ints
    float2* tpw      = (float2*)ctmp;            // 16384 float2

    k_gate<<<dim3(B_ * N_ / 4), dim3(256), 0, stream>>>(tokens, gate_w, gate_b,
                                                        geno_vec, geno_w, geno_b,
                                                        tpi, tpw, tb2);
    k_build<<<dim3(B_), dim3(1024), 0, stream>>>(tpi, tpw, cnt, mass, ln, lw,
                                                 hsum, ctmp);
    k_w1t<<<dim3(8, 8, K_), dim3(256), 0, stream>>>(w1, w1t2);
    k_ffn1<<<dim3(B_ * K_, N_ / 64, 2), dim3(256), 0, stream>>>(tb2, w1t2, b1,
                                                                cnt, ln, lw, hsum);
    k_comb<<<dim3(8, K_, 8), dim3(256), 0, stream>>>(hsum, w2, ctmp);
    k_fin<<<dim3(128), dim3(256), 0, stream>>>(ctmp, b2, mass, cnt, out);
}

// Round 9
// 183.088 us; speedup vs baseline: 5.9479x; 1.0356x over previous
//
#include <hip/hip_runtime.h>
#include <math.h>

#define B_ 8
#define N_ 2048
#define C_ 512
#define K_ 8
#define EPS 1e-6f
#define GENO_RATIO 0.1f

typedef __bf16 bf16x8 __attribute__((ext_vector_type(8)));
typedef float f32x4 __attribute__((ext_vector_type(4)));

__device__ __forceinline__ ushort f2bf(float x) {
    unsigned int u = __float_as_uint(x);
    u += 0x7fffu + ((u >> 16) & 1u);   // RNE (inputs are finite)
    return (ushort)(u >> 16);
}

__device__ __forceinline__ bf16x8 as_bf(uint4 x) {
    union { uint4 u; bf16x8 b; } t; t.u = x; return t.b;
}

// ---------------------------------------------------------------------------
// ws layout (float element offsets):
// [64,128)             cnt (int)   [B,K]
// [128,192)            mass        [B,K]
// [192,32960)          hsum        [B,K,C]    (tpi overlays hsum[0:16384))
// [32960,65728)        ctmp        [B,K,C]    (tpw overlays all of ctmp)
// [65728,196800)       lw          [B,K,N]
// [196800,327872)      ln (int)    [B,K,N]
// [327872,1376448)     w1t2 (bf16) [K][16 cb][512 n][32 cc]   4 MB  (K-tiled)
// [1376448,5570752)    tb2  (bf16) [B][16 cb][2048 n][32 cc]  16.8 MB
// ---------------------------------------------------------------------------

// fused: gating (+geno, + bf16 K-tiled token copy) for blocks [0,4096);
// w1 transpose+convert for blocks [4096,4608).
__global__ __launch_bounds__(256) void k_prep(const float* __restrict__ tokens,
                                              const float* __restrict__ gate_w,
                                              const float* __restrict__ gate_b,
                                              const float* __restrict__ geno_vec,
                                              const float* __restrict__ geno_w,
                                              const float* __restrict__ geno_b,
                                              const float* __restrict__ w1,
                                              int* __restrict__ tpi,
                                              float2* __restrict__ tpw,
                                              ushort* __restrict__ tb2,
                                              ushort* __restrict__ w1t2) {
    __shared__ float smem[8192];   // 32 KB, shared by both bodies
    int tid = threadIdx.x;
    if (blockIdx.x < 4096) {
        float* gwT = smem;          // [8][512] gate_w transposed
        float* qwT = smem + 4096;   // [8][512] geno_w transposed
        for (int i = tid; i < 1024; i += 256) {
            int c = i >> 1, j0 = (i & 1) * 4;
            float4 v = *(const float4*)(gate_w + i * 4);
            gwT[(j0 + 0) * 512 + c] = v.x; gwT[(j0 + 1) * 512 + c] = v.y;
            gwT[(j0 + 2) * 512 + c] = v.z; gwT[(j0 + 3) * 512 + c] = v.w;
            float4 u = *(const float4*)(geno_w + i * 4);
            qwT[(j0 + 0) * 512 + c] = u.x; qwT[(j0 + 1) * 512 + c] = u.y;
            qwT[(j0 + 2) * 512 + c] = u.z; qwT[(j0 + 3) * 512 + c] = u.w;
        }
        __syncthreads();

        int wave = tid >> 6, lane = tid & 63;
        int t = blockIdx.x * 4 + wave;
        int b = t >> 11;
        int n = t & 2047;
        int c0 = lane * 8;
        const float* trow = tokens + (size_t)t * C_;
        float4 v0 = *(const float4*)(trow + c0);
        float4 v1 = *(const float4*)(trow + c0 + 4);
        const float* grow = geno_vec + (size_t)b * C_;
        float4 gy0 = *(const float4*)(grow + c0);
        float4 gy1 = *(const float4*)(grow + c0 + 4);
        float tv[8] = {v0.x, v0.y, v0.z, v0.w, v1.x, v1.y, v1.z, v1.w};
        float gv[8] = {gy0.x, gy0.y, gy0.z, gy0.w, gy1.x, gy1.y, gy1.z, gy1.w};

        float acc[8];
        #pragma unroll
        for (int j = 0; j < 8; ++j) {
            const float* wj = gwT + j * 512 + c0;
            const float* qj = qwT + j * 512 + c0;
            float4 w0 = *(const float4*)(wj);
            float4 w1v = *(const float4*)(wj + 4);
            float4 q0 = *(const float4*)(qj);
            float4 q1 = *(const float4*)(qj + 4);
            float a = 0.f, g = 0.f;
            a = fmaf(tv[0], w0.x, a); a = fmaf(tv[1], w0.y, a);
            a = fmaf(tv[2], w0.z, a); a = fmaf(tv[3], w0.w, a);
            a = fmaf(tv[4], w1v.x, a); a = fmaf(tv[5], w1v.y, a);
            a = fmaf(tv[6], w1v.z, a); a = fmaf(tv[7], w1v.w, a);
            g = fmaf(gv[0], q0.x, g); g = fmaf(gv[1], q0.y, g);
            g = fmaf(gv[2], q0.z, g); g = fmaf(gv[3], q0.w, g);
            g = fmaf(gv[4], q1.x, g); g = fmaf(gv[5], q1.y, g);
            g = fmaf(gv[6], q1.z, g); g = fmaf(gv[7], q1.w, g);
            acc[j] = fmaf(GENO_RATIO, g, a);
        }
        {
            int cb = c0 >> 5, cc = c0 & 31;
            uint4 o;
            o.x = (unsigned)f2bf(tv[0]) | ((unsigned)f2bf(tv[1]) << 16);
            o.y = (unsigned)f2bf(tv[2]) | ((unsigned)f2bf(tv[3]) << 16);
            o.z = (unsigned)f2bf(tv[4]) | ((unsigned)f2bf(tv[5]) << 16);
            o.w = (unsigned)f2bf(tv[6]) | ((unsigned)f2bf(tv[7]) << 16);
            *(uint4*)(tb2 + ((size_t)(b * 16 + cb) * 2048 + n) * 32 + cc) = o;
        }
        #pragma unroll
        for (int off = 32; off > 0; off >>= 1) {
            #pragma unroll
            for (int j = 0; j < 8; ++j) acc[j] += __shfl_xor(acc[j], off, 64);
        }
        if (lane == 0) {
            float lg[8];
            #pragma unroll
            for (int j = 0; j < 8; ++j)
                lg[j] = acc[j] + gate_b[j] + GENO_RATIO * geno_b[j];
            int i0 = 0; float v0m = lg[0];
            #pragma unroll
            for (int j = 1; j < 8; ++j) if (lg[j] > v0m) { v0m = lg[j]; i0 = j; }
            int i1 = -1; float v1m = -1e30f;
            #pragma unroll
            for (int j = 0; j < 8; ++j) if (j != i0 && lg[j] > v1m) { v1m = lg[j]; i1 = j; }
            float e = expf(v1m - v0m);
            float w0 = 1.f / (1.f + e);
            float w1s = e / (1.f + e);
            w0 = fmaxf(w0, EPS); w1s = fmaxf(w1s, EPS);
            float s = w0 + w1s; w0 /= s; w1s /= s;
            tpi[t] = i0 | (i1 << 4);
            tpw[t] = make_float2(w0, w1s);
        }
    } else {
        // w1 transpose+convert: w1t2[k][cb][n][cc] = bf16(w1[k][cb*32+cc][n])
        int id2 = blockIdx.x - 4096;
        int k = id2 >> 6;
        int c0 = ((id2 >> 3) & 7) * 64;
        int n0 = (id2 & 7) * 64;
        float (*tile)[65] = (float(*)[65])smem;
        int tr = tid >> 4;          // 0..15
        int tc4 = (tid & 15) * 4;   // 0..60
        const float* src = w1 + (size_t)k * C_ * C_;
        #pragma unroll
        for (int i = 0; i < 4; ++i) {
            int c = c0 + tr + i * 16;
            float4 v = *(const float4*)(src + (size_t)c * C_ + n0 + tc4);
            tile[tr + i * 16][tc4 + 0] = v.x; tile[tr + i * 16][tc4 + 1] = v.y;
            tile[tr + i * 16][tc4 + 2] = v.z; tile[tr + i * 16][tc4 + 3] = v.w;
        }
        __syncthreads();
        #pragma unroll
        for (int i = 0; i < 4; ++i) {
            int rr = tr + i * 16;
            int n = n0 + rr;
            int c = c0 + tc4;
            int cb = c >> 5, cc = c & 31;
            uint2 o;
            o.x = (unsigned)f2bf(tile[tc4 + 0][rr]) | ((unsigned)f2bf(tile[tc4 + 1][rr]) << 16);
            o.y = (unsigned)f2bf(tile[tc4 + 2][rr]) | ((unsigned)f2bf(tile[tc4 + 3][rr]) << 16);
            *(uint2*)(w1t2 + ((size_t)(k * 16 + cb) * 512 + n) * 32 + cc) = o;
        }
    }
}

// list build + zero hsum/ctmp. One block per batch b; ballot-aggregated LDS
// atomics; reads its own tpi/tpw slice, syncs, then zeroes overlaid regions.
__global__ __launch_bounds__(1024) void k_build(const int* __restrict__ tpi,
                                                const float2* __restrict__ tpw,
                                                int* __restrict__ cnt,
                                                float* __restrict__ mass,
                                                int* __restrict__ ln,
                                                float* __restrict__ lw,
                                                float* __restrict__ hsum,
                                                float* __restrict__ ctmp) {
    int b = blockIdx.x;
    __shared__ int   lcnt[8];
    __shared__ float lmass[8];
    int tid = threadIdx.x;
    if (tid < 8) { lcnt[tid] = 0; lmass[tid] = 0.f; }

    int pk[2]; float2 w[2];
    #pragma unroll
    for (int it = 0; it < 2; ++it) {
        int n = it * 1024 + tid;
        pk[it] = tpi[b * N_ + n];
        w[it]  = tpw[b * N_ + n];
    }
    __syncthreads();

    {
        float4 z = {0.f, 0.f, 0.f, 0.f};
        float4* h4 = (float4*)hsum;
        if (tid < 512) h4[b * 512 + tid] = z;
        else           h4[4096 + b * 512 + (tid - 512)] = z;
        float4* c4 = (float4*)ctmp;
        c4[b * 1024 + tid] = z;
    }

    int lane = tid & 63;
    unsigned long long lt = (1ull << lane) - 1ull;
    #pragma unroll
    for (int it = 0; it < 2; ++it) {
        int n = it * 1024 + tid;
        int i0 = pk[it] & 15, i1 = pk[it] >> 4;
        #pragma unroll
        for (int kk = 0; kk < 8; ++kk) {
            unsigned long long m0 = __ballot(i0 == kk);
            unsigned long long m1 = __ballot(i1 == kk);
            int c0 = __popcll(m0), c1 = __popcll(m1);
            int base = 0;
            if (lane == 0 && (c0 + c1) > 0) base = atomicAdd(&lcnt[kk], c0 + c1);
            base = __shfl(base, 0, 64);
            int pbase = (b * 8 + kk) * N_;
            if (i0 == kk) {
                int pos = base + __popcll(m0 & lt);
                ln[pbase + pos] = n; lw[pbase + pos] = w[it].x;
            }
            if (i1 == kk) {
                int pos = base + c0 + __popcll(m1 & lt);
                ln[pbase + pos] = n; lw[pbase + pos] = w[it].y;
            }
            float s = (i0 == kk ? w[it].x : 0.f) + (i1 == kk ? w[it].y : 0.f);
            #pragma unroll
            for (int off = 32; off > 0; off >>= 1) s += __shfl_xor(s, off, 64);
            if (lane == 0 && s != 0.f) atomicAdd(&lmass[kk], s);
        }
    }
    __syncthreads();
    if (tid < 8) {
        cnt[b * 8 + tid]  = lcnt[tid];
        mass[b * 8 + tid] = lmass[tid];
    }
}

// grouped GEMM1, MFMA bf16. 1-D XCD-affine grid: id = b + 8*(k + 8*m), so
// id&7 = b = XCD -> tb2 slice stays L2-resident per XCD. Wave owns 128 ch
// (32 MFMA per 8 loads). A: LDS dbuf staged (runtime loop, 1 barrier/iter);
// B: loop-carried VGPR dbuf.
__global__ __launch_bounds__(256, 2) void k_ffn1(const ushort* __restrict__ tb2,
                                                 const ushort* __restrict__ w1t2,
                                                 const float* __restrict__ b1,
                                                 const int* __restrict__ cnt,
                                                 const int* __restrict__ ln,
                                                 const float* __restrict__ lw,
                                                 float* __restrict__ hsum) {
    int id = blockIdx.x;
    int b = id & 7, k = (id >> 3) & 7, m = id >> 6;
    int p = b * 8 + k;
    int count = cnt[p];
    int m0 = m * 64;
    if (m0 >= count) return;

    __shared__ ushort As[2][64 * 34];   // 64 rows x 32 bf16, stride 34 (68B)
    __shared__ int   ns_s[64];
    __shared__ float wls_s[64];
    int tid = threadIdx.x;
    if (tid < 64) {
        int mi = m0 + tid;
        bool v = mi < count;
        ns_s[tid]  = v ? ln[p * N_ + mi] : 0;
        wls_s[tid] = v ? lw[p * N_ + mi] : 0.f;
    }
    __syncthreads();

    int wv = tid >> 6, lane = tid & 63;
    int ln15 = lane & 15, q = lane >> 4;

    // A staging: thread handles row r, 16B piece q4 (chunk stride 65536 ush)
    int r = tid >> 2, q4 = tid & 3;
    const ushort* agbase = tb2 + ((size_t)(b * 16) * 2048 + ns_s[r]) * 32 + q4 * 8;
    // B: wave wv owns channels wv*128 + j*16 + ln15, j=0..7
    const ushort* bb0 = w1t2 + ((size_t)(k * 16) * 512 + wv * 128 + ln15) * 32 + q * 8;

    f32x4 acc[4][8];
    #pragma unroll
    for (int mt = 0; mt < 4; ++mt)
        #pragma unroll
        for (int j = 0; j < 8; ++j) acc[mt][j] = (f32x4){0.f, 0.f, 0.f, 0.f};

    uint4 b_cur[8], b_nxt[8];
    {
        uint4 av = *(const uint4*)(agbase);
        *(uint4*)&As[0][r * 34 + q4 * 8] = av;
    }
    #pragma unroll
    for (int j = 0; j < 8; ++j) b_cur[j] = *(const uint4*)(bb0 + j * 512);
    __syncthreads();

    #pragma unroll 1
    for (int cb = 0; cb < 16; ++cb) {
        uint4 a_nx;
        if (cb < 15) {
            a_nx = *(const uint4*)(agbase + (size_t)(cb + 1) * 65536);
            #pragma unroll
            for (int j = 0; j < 8; ++j)
                b_nxt[j] = *(const uint4*)(bb0 + (size_t)(cb + 1) * 16384 + j * 512);
        }
        const ushort* ab = &As[cb & 1][0];
        bf16x8 afrag[4];
        #pragma unroll
        for (int mt = 0; mt < 4; ++mt)
            afrag[mt] = *(const bf16x8*)(ab + (mt * 16 + ln15) * 34 + q * 8);
        #pragma unroll
        for (int mt = 0; mt < 4; ++mt)
            #pragma unroll
            for (int j = 0; j < 8; ++j)
                acc[mt][j] = __builtin_amdgcn_mfma_f32_16x16x32_bf16(
                    afrag[mt], as_bf(b_cur[j]), acc[mt][j], 0, 0, 0);
        if (cb < 15) {
            *(uint4*)&As[(cb + 1) & 1][r * 34 + q4 * 8] = a_nx;
            #pragma unroll
            for (int j = 0; j < 8; ++j) b_cur[j] = b_nxt[j];
        }
        __syncthreads();
    }

    // epilogue: bias+relu+gate-weight; reduce 4 q-lanes; 1 atomic per column
    float wrow[4][4];
    #pragma unroll
    for (int mt = 0; mt < 4; ++mt)
        #pragma unroll
        for (int rr = 0; rr < 4; ++rr) wrow[mt][rr] = wls_s[mt * 16 + q * 4 + rr];
    const float* b1k = b1 + k * C_;
    float* hp = hsum + (size_t)p * C_;
    #pragma unroll
    for (int j = 0; j < 8; ++j) {
        int n = wv * 128 + j * 16 + ln15;
        float bias = b1k[n];
        float s = 0.f;
        #pragma unroll
        for (int mt = 0; mt < 4; ++mt)
            #pragma unroll
            for (int rr = 0; rr < 4; ++rr)
                s += wrow[mt][rr] * fmaxf(acc[mt][j][rr] + bias, 0.f);
        s += __shfl_xor(s, 16, 64);
        s += __shfl_xor(s, 32, 64);
        if (q == 0) atomicAdd(&hp[n], s);
    }
}

// combine partials: ctmp[b,k,e] += sum_{c in 64-chunk} hsum[b,k,c]*w2[k,c,e]
__global__ __launch_bounds__(256) void k_comb(const float* __restrict__ hsum,
                                              const float* __restrict__ w2,
                                              float* __restrict__ ctmp) {
    int et = blockIdx.x, k = blockIdx.y, cc = blockIdx.z;
    int e0 = et * 64, c0 = cc * 64;
    __shared__ float hs[8][64];
    int t = threadIdx.x;
    for (int i = t; i < 512; i += 256) {
        int b = i >> 6, c = i & 63;
        hs[b][c] = hsum[(size_t)((b * 8 + k) << 9) + c0 + c];
    }
    __syncthreads();
    int e = e0 + (t & 63); int g = t >> 6;
    float a0 = 0.f, a1 = 0.f;
    const float* w2p = w2 + (size_t)k * C_ * C_ + e;
    #pragma unroll 4
    for (int c = 0; c < 64; ++c) {
        float wv = w2p[(size_t)(c0 + c) * C_];
        a0 = fmaf(hs[g][c], wv, a0);
        a1 = fmaf(hs[g + 4][c], wv, a1);
    }
    atomicAdd(&ctmp[((g * 8 + k) << 9) + e], a0);
    atomicAdd(&ctmp[(((g + 4) * 8 + k) << 9) + e], a1);
}

// finalize: centers = (ctmp + b2*mass)/max(mass,eps); thread0 writes lb_loss
__global__ __launch_bounds__(256) void k_fin(const float* __restrict__ ctmp,
                                             const float* __restrict__ b2,
                                             const float* __restrict__ mass,
                                             const int* __restrict__ cnt,
                                             float* __restrict__ out) {
    int i = blockIdx.x * 256 + threadIdx.x;  // 0..32767
    int b = i >> 12; int ke = i & 4095; int k = ke >> 9;
    float m = mass[b * 8 + k];
    out[i] = (ctmp[i] + b2[ke] * m) / fmaxf(m, EPS);
    if (i == 0) {
        float u[8]; float s = 0.f;
        for (int kk = 0; kk < 8; ++kk) {
            int ck = 0;
            for (int bb = 0; bb < 8; ++bb) ck += cnt[bb * K_ + kk];
            u[kk] = (float)ck / (float)(B_ * N_);
            s += u[kk];
        }
        float mean = s / 8.f;
        float var = 0.f;
        for (int kk = 0; kk < 8; ++kk) { float d = u[kk] - mean; var += d * d; }
        var /= 8.f;
        float denom = mean + EPS;
        out[B_ * K_ * C_] = var / (denom * denom);
    }
}

extern "C" void kernel_launch(void* const* d_in, const int* in_sizes, int n_in,
                              void* d_out, int out_size, void* d_ws, size_t ws_size,
                              hipStream_t stream) {
    (void)in_sizes; (void)n_in; (void)out_size; (void)ws_size;
    const float* tokens   = (const float*)d_in[0];
    const float* geno_vec = (const float*)d_in[1];
    const float* gate_w   = (const float*)d_in[2];
    const float* gate_b   = (const float*)d_in[3];
    const float* geno_w   = (const float*)d_in[4];
    const float* geno_b   = (const float*)d_in[5];
    const float* w1       = (const float*)d_in[6];
    const float* b1       = (const float*)d_in[7];
    const float* w2       = (const float*)d_in[8];
    const float* b2       = (const float*)d_in[9];
    float* out = (float*)d_out;
    float* ws  = (float*)d_ws;

    int*    cnt      = (int*)(ws + 64);          // 64
    float*  mass     = ws + 128;                 // 64
    float*  hsum     = ws + 192;                 // 32768
    float*  ctmp     = ws + 32960;               // 32768
    float*  lw       = ws + 65728;               // 131072
    int*    ln       = (int*)(ws + 196800);      // 131072
    ushort* w1t2     = (ushort*)(ws + 327872);   // 2,097,152 bf16 (4 MB)
    ushort* tb2      = (ushort*)(ws + 1376448);  // 8,388,608 bf16 (16.8 MB)
    int*    tpi      = (int*)hsum;               // overlay, resolved in k_build
    float2* tpw      = (float2*)ctmp;            // overlay, resolved in k_build

    k_prep<<<dim3(4096 + 512), dim3(256), 0, stream>>>(tokens, gate_w, gate_b,
                                                       geno_vec, geno_w, geno_b,
                                                       w1, tpi, tpw, tb2, w1t2);
    k_build<<<dim3(B_), dim3(1024), 0, stream>>>(tpi, tpw, cnt, mass, ln, lw,
                                                 hsum, ctmp);
    k_ffn1<<<dim3(B_ * K_ * (N_ / 64)), dim3(256), 0, stream>>>(tb2, w1t2, b1,
                                                                cnt, ln, lw, hsum);
    k_comb<<<dim3(8, K_, 8), dim3(256), 0, stream>>>(hsum, w2, ctmp);
    k_fin<<<dim3(128), dim3(256), 0, stream>>>(ctmp, b2, mass, cnt, out);
}